// Round 2
// 694.448 us; speedup vs baseline: 1.0745x; 1.0745x over previous
//
#include <hip/hip_runtime.h>

// RNNSequenceClassifier on MI355X. Inputs/outputs are FLOAT32 (proven R4/R5).
// prep -> graph/t_feat (fused entity-transform MFMA) -> xw GEMM (MFMA, gate-interleaved
// bf16 out) -> prep2 (whh -> i8 MFMA B-frags, gate-interleaved, x1024 scaled) ->
// i8-MFMA LSTM scan (weights register-resident, single barrier/step, double-buffered
// h, in-wave gate transpose) -> attention/head.

typedef unsigned short ushort_t;
typedef unsigned char uchar_t;
typedef __bf16 bf16x8 __attribute__((ext_vector_type(8)));
typedef float f32x4 __attribute__((ext_vector_type(4)));
typedef int i32x4 __attribute__((ext_vector_type(4)));

#define NENT 200000
#define NVOC 50000
#define NREL 500
#define KPAD 512

__device__ __forceinline__ float b2f(ushort_t u) {
    return __uint_as_float(((unsigned)u) << 16);
}
__device__ __forceinline__ ushort_t f2b(float f) {
    unsigned u = __float_as_uint(f);
    unsigned r = (u + 0x7FFFu + ((u >> 16) & 1u)) >> 16;
    return (ushort_t)r;
}
__device__ __forceinline__ float sigm(float x) {
    return __builtin_amdgcn_rcpf(1.f + __expf(-x));
}
__device__ __forceinline__ float tanh_fast(float x) {
    float xx = fminf(fmaxf(x, -15.f), 15.f);
    float t = __expf(2.f * xx);
    return 1.f - 2.f * __builtin_amdgcn_rcpf(t + 1.f);
}
// adaptive int read: int32 (di==0) or int64-low-word (di==1)
__device__ __forceinline__ int iacc(const void* p, long long i, int di) {
    return di ? ((const int*)p)[2 * i] : ((const int*)p)[i];
}

// ---------------- sentinel (f32 out) ------------------------------------------------
__global__ void k_sentinel(float* __restrict__ out, int n, float val) {
    int i = blockIdx.x * 256 + threadIdx.x;
    if (i < n) out[i] = val;
}

// ---------------- tiny int-dtype probe ----------------------------------------------
__global__ void k_det(const int* __restrict__ triples, unsigned* __restrict__ dflag) {
    __shared__ int cnt;
    int tid = threadIdx.x;
    if (tid == 0) cnt = 0;
    __syncthreads();
    int nz = 0;
    for (int i = tid; i < 1500; i += 256)
        if (triples[2 * i + 1] != 0) nz++;
    if (nz) atomicAdd(&cnt, nz);
    __syncthreads();
    if (tid == 0) *dflag = (cnt == 0) ? 2u : 0u;  // bit1: ints are i64
}

// ---------------- prep: Wb[112][256], trelP[500][112], wihT[512][1024] --------------
__global__ void k_prep(const float* __restrict__ Went, const float* __restrict__ wih,
                       const float* __restrict__ relE,
                       ushort_t* __restrict__ Wb, ushort_t* __restrict__ wihT,
                       float* __restrict__ trelP) {
    int i = blockIdx.x * 256 + threadIdx.x;
    int stride = gridDim.x * 256;
    if (i < 112 * 256) {
        int n = i >> 8, k = i & 255;
        float v = 0.f;
        if (n < 100) {
            if (k < 100) v = Went[n * 200 + k];
            else if (k >= 128 && k < 228) v = Went[n * 200 + 100 + (k - 128)];
        }
        Wb[i] = f2b(v);
    }
    for (int j = i; j < 500 * 128; j += stride) {
        int r_ = j >> 7, d = j & 127;
        if (d < 112) trelP[r_ * 112 + d] = (d < 100) ? tanhf(relE[r_ * 100 + d]) : 0.f;
    }
    for (int j = i; j < 512 * 1024; j += stride) {
        int k = j >> 10, n = j & 1023;
        wihT[j] = (k < 500) ? f2b(wih[(long long)n * 500 + k]) : (ushort_t)0;
    }
}

// ---------------- prep2: whhI8 = rint(1024*w_hh) as i8 in MFMA B-fragment order -----
// gate-interleaved n' = u*4 + g  (orig row n = g*256 + u), frag f = ntg*4 + kt;
// lane l, byte j<16: B[n' = ntg*16 + (l&15)][k = kt*64 + (l>>4)*16 + j]
__global__ void k_prep2(const float* __restrict__ whh, uchar_t* __restrict__ whhI8) {
    int j = blockIdx.x * 256 + threadIdx.x;  // < 262144
    int f = j >> 10, r = j & 1023;
    int lane = r >> 4, jj = r & 15;
    int ntg = f >> 2, kt = f & 3;
    int np = ntg * 16 + (lane & 15);
    int k = kt * 64 + ((lane >> 4) << 4) + jj;
    int u = np >> 2, gg = np & 3;
    int qv = __float2int_rn(whh[(gg * 256 + u) * 256 + k] * 1024.f);
    qv = min(max(qv, -127), 127);
    whhI8[j] = (uchar_t)(qv & 0xFF);
}

// ---------------- graph kernel: one block per (b,s), fused transform MFMA -----------
__global__ __launch_bounds__(128) void k_graph(const void* __restrict__ inputs,
                                               const void* __restrict__ triples,
                                               const void* __restrict__ id2,
                                               const float* __restrict__ wordE,
                                               const float* __restrict__ entE,
                                               const ushort_t* __restrict__ Wb,
                                               const float* __restrict__ trelP,
                                               ushort_t* __restrict__ tfeat,
                                               const unsigned* __restrict__ dflag) {
    int di = ((*dflag) >> 1) & 1;
    int bs = blockIdx.x;
    int tid = threadIdx.x;
    __shared__ __align__(16) ushort_t As[32][256];  // [t][k]: head k<100, tail 128..227
    __shared__ int rids[32];
    __shared__ float e_sm[32];
    __shared__ float alpha[32];
    __shared__ int vflag;
    if (tid == 0) vflag = 0;
    __syncthreads();
    int t = tid >> 2, l4 = tid & 3;
    long long base3 = ((long long)bs * 32 + t) * 3;
    int hid = iacc(triples, base3, di);
    int tl = iacc(triples, base3 + 1, di);
    int rid = iacc(triples, base3 + 2, di);
    hid = min(max(hid, 0), NENT - 1);
    tl = min(max(tl, 0), NENT - 1);
    rid = min(max(rid, 0), NREL - 1);
    if (l4 == 0) {
        rids[t] = rid;
        if (iacc(id2, (long long)bs * 32 + t, di) != -1) vflag = 1;
    }
    for (int k = l4; k < 256; k += 4) {
        float v = 0.f;
        if (k < 100) v = entE[(long long)hid * 100 + k];
        else if (k >= 128 && k < 228) v = entE[(long long)tl * 100 + (k - 128)];
        As[t][k] = f2b(v);
    }
    __syncthreads();
    int wave = tid >> 6, lane = tid & 63, m16 = lane & 15, q = lane >> 4;
    f32x4 acc[7];
#pragma unroll
    for (int nt = 0; nt < 7; nt++) acc[nt] = {0.f, 0.f, 0.f, 0.f};
#pragma unroll
    for (int ks = 0; ks < 8; ++ks) {
        bf16x8 af = *reinterpret_cast<const bf16x8*>(&As[wave * 16 + m16][ks * 32 + q * 8]);
#pragma unroll
        for (int nt = 0; nt < 7; ++nt) {
            bf16x8 bf_ = *reinterpret_cast<const bf16x8*>(&Wb[(nt * 16 + m16) * 256 + ks * 32 + q * 8]);
            acc[nt] = __builtin_amdgcn_mfma_f32_16x16x32_bf16(af, bf_, acc[nt], 0, 0, 0);
        }
    }
#pragma unroll
    for (int rr = 0; rr < 4; ++rr) {
        int m = wave * 16 + q * 4 + rr;
        const float* tr = trelP + rids[m] * 112;
        float s = 0.f;
#pragma unroll
        for (int nt = 0; nt < 7; ++nt) s += tanhf(acc[nt][rr]) * tr[nt * 16 + m16];
        s += __shfl_xor(s, 1);
        s += __shfl_xor(s, 2);
        s += __shfl_xor(s, 4);
        s += __shfl_xor(s, 8);
        if (m16 == 0) e_sm[m] = s;
    }
    __syncthreads();
    if (tid < 32) {
        float v = e_sm[tid];
        float mx = v;
        for (int off = 16; off >= 1; off >>= 1) mx = fmaxf(mx, __shfl_xor(mx, off));
        float ex = __expf(v - mx);
        float sm = ex;
        for (int off = 16; off >= 1; off >>= 1) sm += __shfl_xor(sm, off);
        alpha[tid] = ex / sm;
    }
    __syncthreads();
    float scale = vflag ? 1.f : 0.f;
    long long row = (long long)bs * KPAD;
    for (int k = tid; k < 200; k += 128) {
        int kk = (k < 100) ? k : (k + 28);
        float ge = 0.f;
#pragma unroll 8
        for (int tt = 0; tt < 32; ++tt) ge += alpha[tt] * b2f(As[tt][kk]);
        tfeat[row + 300 + k] = f2b(ge * scale);
    }
    int w = iacc(inputs, bs, di);
    w = min(max(w, 0), NVOC - 1);
    for (int j = tid; j < 300; j += 128) tfeat[row + j] = f2b(wordE[(long long)w * 300 + j]);
    if (tid < 12) tfeat[row + 500 + tid] = 0;
}

// ---------------- GEMM: xw = tfeat @ w_ihT + b_ih + b_hh (bf16, gate-interleaved) ---
// store layout: xwB[i*1024 + (n&255)*4 + (n>>8)]  (unit-major, 4 gates adjacent)
__global__ __launch_bounds__(256) void k_gemm_xw(const ushort_t* __restrict__ A,
                                                 const ushort_t* __restrict__ Bm,
                                                 const float* __restrict__ bih,
                                                 const float* __restrict__ bhh,
                                                 ushort_t* __restrict__ xwB) {
    __shared__ __align__(16) ushort_t As[64 * 32];
    __shared__ __align__(16) ushort_t Bs[64 * 32];
    int tid = threadIdx.x;
    int i0 = blockIdx.x * 64, n0 = blockIdx.y * 64;
    int wave = tid >> 6, lane = tid & 63, m16 = lane & 15, q = lane >> 4;
    f32x4 acc[4];
#pragma unroll
    for (int t = 0; t < 4; t++) acc[t] = {0.f, 0.f, 0.f, 0.f};
    int r = tid >> 2, cq = (tid & 3) * 8;
    int kk = tid >> 3, nn = (tid & 7) * 8;
    for (int kt = 0; kt < 16; ++kt) {
        int k0 = kt * 32;
        {
            const ushort_t* src = A + (i0 + r) * 512 + k0 + cq;
            ushort4 v0 = *(const ushort4*)src;
            ushort4 v1 = *(const ushort4*)(src + 4);
            *(ushort4*)&As[r * 32 + cq] = v0;
            *(ushort4*)&As[r * 32 + cq + 4] = v1;
        }
        {
            const ushort_t* src = Bm + (k0 + kk) * 1024 + n0 + nn;
            ushort4 v0 = *(const ushort4*)(src);
            ushort4 v1 = *(const ushort4*)(src + 4);
            Bs[(nn + 0) * 32 + kk] = v0.x; Bs[(nn + 1) * 32 + kk] = v0.y;
            Bs[(nn + 2) * 32 + kk] = v0.z; Bs[(nn + 3) * 32 + kk] = v0.w;
            Bs[(nn + 4) * 32 + kk] = v1.x; Bs[(nn + 5) * 32 + kk] = v1.y;
            Bs[(nn + 6) * 32 + kk] = v1.z; Bs[(nn + 7) * 32 + kk] = v1.w;
        }
        __syncthreads();
        bf16x8 af = *reinterpret_cast<const bf16x8*>(&As[(wave * 16 + m16) * 32 + q * 8]);
#pragma unroll
        for (int t = 0; t < 4; t++) {
            bf16x8 bf_ = *reinterpret_cast<const bf16x8*>(&Bs[(t * 16 + m16) * 32 + q * 8]);
            acc[t] = __builtin_amdgcn_mfma_f32_16x16x32_bf16(af, bf_, acc[t], 0, 0, 0);
        }
        __syncthreads();
    }
#pragma unroll
    for (int t = 0; t < 4; t++) {
        int n = n0 + t * 16 + m16;
        float bias = bih[n] + bhh[n];
        int ni = ((n & 255) << 2) + (n >> 8);
#pragma unroll
        for (int rr = 0; rr < 4; rr++) {
            int i = i0 + wave * 16 + q * 4 + rr;
            xwB[i * 1024 + ni] = f2b(acc[t][rr] + bias);
        }
    }
}

// ---------------- LSTM scan: 8 blocks x 512 thr, 8 batch rows/block, i8 MFMA --------
// w_hh (x1024, i8, gate-interleaved n'=u*4+g) register-resident: 8 waves x 8 ntg x
// 4 kt x 16B = 256 KB/block. h double-buffered in LDS as i8 (x127). One barrier/step
// (raw s_barrier, lgkm-only drain); gates combined in-wave via 4x4 lane transpose;
// next-step xw prefetched BEFORE the hallB stores so vmcnt never waits on stores.
__global__ __launch_bounds__(512, 2) void k_lstm(const ushort_t* __restrict__ xwB,
                                                 const uchar_t* __restrict__ whhI8,
                                                 const void* __restrict__ lengths,
                                                 ushort_t* __restrict__ hallB,
                                                 const unsigned* __restrict__ dflag) {
    const int LDH = 272;  // row stride bytes, 16-aligned for ds_read_b128
    int di = ((*dflag) >> 1) & 1;
    int b0 = blockIdx.x * 8;
    int tid = threadIdx.x;
    int wave = tid >> 6, lane = tid & 63;
    int c16 = lane & 15, q = lane >> 4;
    int g = lane & 3, ul = (lane >> 2) & 3;
    __shared__ __align__(16) uchar_t hsm[2][16 * 272];  // h*127 as i8; rows 8..15 stay 0
    for (int j = tid; j < 2 * 16 * 272; j += 512) ((uchar_t*)hsm)[j] = 0;
    // register-resident weight fragments (once): wreg[i][kt] for ntg = wave*8+i
    i32x4 wreg[8][4];
    {
        const uchar_t* wp = whhI8 + (((long long)(wave * 8) * 4) * 64 + lane) * 16;
#pragma unroll
        for (int i = 0; i < 8; ++i)
#pragma unroll
            for (int kt = 0; kt < 4; ++kt)
                wreg[i][kt] = *(const i32x4*)(wp + (((i << 2) + kt) << 10));
    }
    int row = ((q & 1) << 2) + g;          // batch row (0..7) this lane updates
    int ipar = (q < 2) ? 0 : 1;            // which half of the MFMA pair
    int ub = (wave * 8 + ipar) * 4 + ul;   // unit for pair p: ub + p*8
    int len = iacc(lengths, b0 + row, di);
    float cst[4] = {0.f, 0.f, 0.f, 0.f};
    const float S = 1.f / (127.f * 1024.f);
    long long xrow0 = ((long long)((b0 + row) * 128) << 10) + (ub << 2);
    ushort4 xv[4], xn[4];
#pragma unroll
    for (int p = 0; p < 4; ++p) xv[p] = *(const ushort4*)(xwB + xrow0 + (p << 5));
    __syncthreads();
    for (int s = 0; s < 128; ++s) {
        // phase A operands: h rows (A-frag: row=c16, k = kt*64 + q*16 + j)
        const uchar_t* hb = &hsm[s & 1][c16 * LDH];
        i32x4 afr[4];
#pragma unroll
        for (int kt = 0; kt < 4; ++kt)
            afr[kt] = *(const i32x4*)(hb + kt * 64 + q * 16);
        // prefetch next step's xw early (before any stores this step)
        int sn = (s < 127) ? s + 1 : 127;
        long long xrn = xrow0 + ((long long)sn << 10);
#pragma unroll
        for (int p = 0; p < 4; ++p) xn[p] = *(const ushort4*)(xwB + xrn + (p << 5));
        uchar_t* hw = &hsm[(s & 1) ^ 1][0];
#pragma unroll
        for (int p = 0; p < 4; ++p) {
            i32x4 aA = {0, 0, 0, 0}, aB = {0, 0, 0, 0};
#pragma unroll
            for (int kt = 0; kt < 4; ++kt) {
                aA = __builtin_amdgcn_mfma_i32_16x16x64_i8(afr[kt], wreg[2 * p][kt], aA, 0, 0, 0);
                aB = __builtin_amdgcn_mfma_i32_16x16x64_i8(afr[kt], wreg[2 * p + 1][kt], aB, 0, 0, 0);
            }
            // hand aB's real rows (held in q<2 lanes) to the q>=2 half-wave
            int s0 = __shfl_xor(aB[0], 32);
            int s1 = __shfl_xor(aB[1], 32);
            int s2 = __shfl_xor(aB[2], 32);
            int s3 = __shfl_xor(aB[3], 32);
            int t0 = (q < 2) ? aA[0] : s0;
            int t1 = (q < 2) ? aA[1] : s1;
            int t2 = (q < 2) ? aA[2] : s2;
            int t3 = (q < 2) ? aA[3] : s3;
            // 4x4 transpose within 4-lane groups: regs (rows) <-> lanes (gates)
            int u0 = (g & 2) ? t0 : t2;
            int u1 = (g & 2) ? t1 : t3;
            int r0 = __shfl_xor(u0, 2), r1 = __shfl_xor(u1, 2);
            if (g & 2) { t0 = r0; t1 = r1; } else { t2 = r0; t3 = r1; }
            int u2 = (g & 1) ? t0 : t1;
            int u3 = (g & 1) ? t2 : t3;
            int r2 = __shfl_xor(u2, 1), r3 = __shfl_xor(u3, 1);
            if (g & 1) { t0 = r2; t2 = r3; } else { t1 = r2; t3 = r3; }
            // t0..t3 = i,f,g,o pre-activations*(127*1024) for (row, unit ub+8p)
            float iv = b2f(xv[p].x) + (float)t0 * S;
            float fv = b2f(xv[p].y) + (float)t1 * S;
            float gv = b2f(xv[p].z) + (float)t2 * S;
            float ov = b2f(xv[p].w) + (float)t3 * S;
            float c = sigm(fv) * cst[p] + sigm(iv) * tanh_fast(gv);
            float h = sigm(ov) * tanh_fast(c);
            cst[p] = c;
            int un = ub + (p << 3);
            hw[row * LDH + un] = (uchar_t)(__float2int_rn(h * 127.f) & 0xFF);
            hallB[((long long)((b0 + row) * 128 + s) << 8) + un] = (s < len) ? f2b(h) : (ushort_t)0;
            xv[p] = xn[p];
        }
        // single barrier/step: drain LDS only (global stores stay in flight)
        asm volatile("s_waitcnt lgkmcnt(0)\n\ts_barrier" ::: "memory");
    }
}

// ---------------- attention + classifier head (f32 out) -----------------------------
__global__ __launch_bounds__(256) void k_att(const ushort_t* __restrict__ hallB,
                                             const float* __restrict__ Watt,
                                             const float* __restrict__ batt,
                                             const float* __restrict__ Wout,
                                             const float* __restrict__ bout,
                                             float* __restrict__ out) {
    int b = blockIdx.x, tid = threadIdx.x;
    __shared__ float waf[256], lg[128], msk[128], ps[128], enc[256], o3[3], red[1];
    waf[tid] = Watt[tid];
    __syncthreads();
    int s = tid >> 1, half = tid & 1;
    const ushort_t* hb = hallB + (b * 128 + s) * 256 + half * 128;
    float part = 0.f;
    for (int j = 0; j < 128; ++j) part += b2f(hb[j]) * waf[half * 128 + j];
    part += __shfl_xor(part, 1);
    if (half == 0) lg[s] = part + batt[0];
    __syncthreads();
    if (tid < 128) {
        float lv = lg[tid];
        float m = (lv != 0.f) ? 1.f : 0.f;
        msk[tid] = m;
        lg[tid] = lv * m;
    }
    __syncthreads();
    if (tid == 0) {
        float mx = -1e30f;
        for (int i = 0; i < 128; ++i) mx = fmaxf(mx, lg[i]);
        red[0] = mx;
    }
    __syncthreads();
    if (tid < 128) ps[tid] = __expf(lg[tid] - red[0]);
    __syncthreads();
    if (tid == 0) {
        float sm = 0.f;
        for (int i = 0; i < 128; ++i) sm += ps[i];
        red[0] = sm;
    }
    __syncthreads();
    if (tid < 128) ps[tid] = ps[tid] / red[0] * msk[tid];
    __syncthreads();
    if (tid == 0) {
        float sm = 0.f;
        for (int i = 0; i < 128; ++i) sm += ps[i];
        red[0] = sm + 1e-13f;
    }
    __syncthreads();
    if (tid < 128) {
        float p = ps[tid] / red[0];
        ps[tid] = p;
        out[192 + b * 128 + tid] = p;
    }
    __syncthreads();
    {
        float ej = 0.f;
        for (int ss = 0; ss < 128; ++ss) ej += ps[ss] * b2f(hallB[(b * 128 + ss) * 256 + tid]);
        enc[tid] = ej;
    }
    __syncthreads();
    if (tid < 3) {
        float a = 0.f;
        for (int j = 0; j < 256; ++j) a += enc[j] * Wout[tid * 256 + j];
        o3[tid] = a + bout[tid];
    }
    __syncthreads();
    if (tid == 0) {
        float m = fmaxf(o3[0], fmaxf(o3[1], o3[2]));
        float l = logf(__expf(o3[0] - m) + __expf(o3[1] - m) + __expf(o3[2] - m)) + m;
        out[b * 3 + 0] = o3[0] - l;
        out[b * 3 + 1] = o3[1] - l;
        out[b * 3 + 2] = o3[2] - l;
    }
}

extern "C" void kernel_launch(void* const* d_in, const int* in_sizes, int n_in,
                              void* d_out, int out_size, void* d_ws, size_t ws_size,
                              hipStream_t stream) {
    float* out = (float*)d_out;
    static const long long EXP[16] = {8192, 786432, 64, 262144, 15000000, 20000000,
                                      50000, 20000, 512000, 262144, 1024, 1024,
                                      256, 1, 768, 3};
    int ob = (out_size + 255) / 256;
    if (n_in != 16 || out_size != 8384) {
        hipLaunchKernelGGL(k_sentinel, dim3(ob), dim3(256), 0, stream, out, out_size, -8192.f);
        return;
    }
    for (int i = 0; i < 16; ++i) {
        if ((long long)in_sizes[i] != EXP[i]) {
            hipLaunchKernelGGL(k_sentinel, dim3(ob), dim3(256), 0, stream, out, out_size,
                               -(4096.f + 32.f * i));
            return;
        }
    }

    const void* inputs = d_in[0];
    const void* triples = d_in[1];
    const void* lengths = d_in[2];
    const void* id2 = d_in[3];
    const float* wordE = (const float*)d_in[4];
    const float* entE = (const float*)d_in[5];
    const float* relE = (const float*)d_in[6];
    const float* Went = (const float*)d_in[7];
    const float* wih = (const float*)d_in[8];
    const float* whh = (const float*)d_in[9];
    const float* bih = (const float*)d_in[10];
    const float* bhh = (const float*)d_in[11];
    const float* Watt = (const float*)d_in[12];
    const float* batt = (const float*)d_in[13];
    const float* Wout = (const float*)d_in[14];
    const float* bout = (const float*)d_in[15];
    char* ws = (char*)d_ws;

    // workspace layout — total 26,496,000 B (< proven 27,028,224)
    constexpr size_t OFF_XW = 0;            // ushort 8192*1024*2 = 16,777,216
    constexpr size_t OFF_TFEAT = 16777216;  // ushort 8192*512*2 = 8,388,608 (hallB overlays)
    constexpr size_t OFF_WIHT = 25165824;   // ushort 512*1024*2 = 1,048,576 (whhI8 overlays after gemm)
    constexpr size_t OFF_WB = 26214400;     // ushort 112*256*2 = 57,344
    constexpr size_t OFF_FLAGS = 26271744;  // u32 dflag
    constexpr size_t OFF_TRELP = 26272000;  // float 500*112*4 = 224,000 -> end 26,496,000
    constexpr size_t WS_NEEDED = 26496000;

    if (ws_size < WS_NEEDED) {
        hipLaunchKernelGGL(k_sentinel, dim3(ob), dim3(256), 0, stream, out, out_size,
                           -(float)(ws_size >> 20));
        return;
    }

    ushort_t* xwB = (ushort_t*)(ws + OFF_XW);
    ushort_t* tfeat = (ushort_t*)(ws + OFF_TFEAT);
    ushort_t* hallB = (ushort_t*)(ws + OFF_TFEAT);  // overlays tfeat after k_gemm_xw
    ushort_t* wihT = (ushort_t*)(ws + OFF_WIHT);
    uchar_t* whhI8 = (uchar_t*)(ws + OFF_WIHT);     // overlays wihT after k_gemm_xw
    ushort_t* Wb = (ushort_t*)(ws + OFF_WB);
    unsigned* dflag = (unsigned*)(ws + OFF_FLAGS);
    float* trelP = (float*)(ws + OFF_TRELP);

    hipLaunchKernelGGL(k_det, dim3(1), dim3(256), 0, stream, (const int*)triples, dflag);
    hipLaunchKernelGGL(k_prep, dim3(2048), dim3(256), 0, stream,
                       Went, wih, relE, Wb, wihT, trelP);
    hipLaunchKernelGGL(k_graph, dim3(8192), dim3(128), 0, stream,
                       inputs, triples, id2, wordE, entE, Wb, trelP, tfeat, dflag);
    hipLaunchKernelGGL(k_gemm_xw, dim3(128, 16), dim3(256), 0, stream,
                       tfeat, wihT, bih, bhh, xwB);
    hipLaunchKernelGGL(k_prep2, dim3(1024), dim3(256), 0, stream, whh, whhI8);
    hipLaunchKernelGGL(k_lstm, dim3(8), dim3(512), 0, stream, xwB, whhI8, lengths, hallB, dflag);
    hipLaunchKernelGGL(k_att, dim3(64), dim3(256), 0, stream, hallB, Watt, batt, Wout, bout, out);
}

// Round 4
// 551.258 us; speedup vs baseline: 1.3537x; 1.2598x over previous
//
#include <hip/hip_runtime.h>

// RNNSequenceClassifier on MI355X. Inputs/outputs are FLOAT32 (proven R4/R5).
// prep -> graph/t_feat (fused entity-transform MFMA) -> xw GEMM (MFMA, gate-interleaved
// bf16 out) -> prep2 (whh -> i8 MFMA B-frags, gate-interleaved, x1024 scaled) ->
// i8-MFMA LSTM scan: 64 blocks x 1 batch row (8x CUs vs R2), weights register-resident,
// gbuf-LDS gate fanout (no shuffle transpose), 2 barriers/step -> attention/head.

typedef unsigned short ushort_t;
typedef unsigned char uchar_t;
typedef __bf16 bf16x8 __attribute__((ext_vector_type(8)));
typedef float f32x4 __attribute__((ext_vector_type(4)));
typedef int i32x4 __attribute__((ext_vector_type(4)));

#define NENT 200000
#define NVOC 50000
#define NREL 500
#define KPAD 512

__device__ __forceinline__ float b2f(ushort_t u) {
    return __uint_as_float(((unsigned)u) << 16);
}
__device__ __forceinline__ ushort_t f2b(float f) {
    unsigned u = __float_as_uint(f);
    unsigned r = (u + 0x7FFFu + ((u >> 16) & 1u)) >> 16;
    return (ushort_t)r;
}
__device__ __forceinline__ float sigm(float x) {
    return __builtin_amdgcn_rcpf(1.f + __expf(-x));
}
__device__ __forceinline__ float tanh_fast(float x) {
    float xx = fminf(fmaxf(x, -15.f), 15.f);
    float t = __expf(2.f * xx);
    return 1.f - 2.f * __builtin_amdgcn_rcpf(t + 1.f);
}
// adaptive int read: int32 (di==0) or int64-low-word (di==1)
__device__ __forceinline__ int iacc(const void* p, long long i, int di) {
    return di ? ((const int*)p)[2 * i] : ((const int*)p)[i];
}

// ---------------- sentinel (f32 out) ------------------------------------------------
__global__ void k_sentinel(float* __restrict__ out, int n, float val) {
    int i = blockIdx.x * 256 + threadIdx.x;
    if (i < n) out[i] = val;
}

// ---------------- tiny int-dtype probe ----------------------------------------------
__global__ void k_det(const int* __restrict__ triples, unsigned* __restrict__ dflag) {
    __shared__ int cnt;
    int tid = threadIdx.x;
    if (tid == 0) cnt = 0;
    __syncthreads();
    int nz = 0;
    for (int i = tid; i < 1500; i += 256)
        if (triples[2 * i + 1] != 0) nz++;
    if (nz) atomicAdd(&cnt, nz);
    __syncthreads();
    if (tid == 0) *dflag = (cnt == 0) ? 2u : 0u;  // bit1: ints are i64
}

// ---------------- prep: Wb[112][256], trelP[500][112], wihT[512][1024] --------------
__global__ void k_prep(const float* __restrict__ Went, const float* __restrict__ wih,
                       const float* __restrict__ relE,
                       ushort_t* __restrict__ Wb, ushort_t* __restrict__ wihT,
                       float* __restrict__ trelP) {
    int i = blockIdx.x * 256 + threadIdx.x;
    int stride = gridDim.x * 256;
    if (i < 112 * 256) {
        int n = i >> 8, k = i & 255;
        float v = 0.f;
        if (n < 100) {
            if (k < 100) v = Went[n * 200 + k];
            else if (k >= 128 && k < 228) v = Went[n * 200 + 100 + (k - 128)];
        }
        Wb[i] = f2b(v);
    }
    for (int j = i; j < 500 * 128; j += stride) {
        int r_ = j >> 7, d = j & 127;
        if (d < 112) trelP[r_ * 112 + d] = (d < 100) ? tanhf(relE[r_ * 100 + d]) : 0.f;
    }
    for (int j = i; j < 512 * 1024; j += stride) {
        int k = j >> 10, n = j & 1023;
        wihT[j] = (k < 500) ? f2b(wih[(long long)n * 500 + k]) : (ushort_t)0;
    }
}

// ---------------- prep2: whhI8 = rint(1024*w_hh) as i8 in MFMA B-fragment order -----
// gate-interleaved n' = u*4 + g  (orig row n = g*256 + u), frag f = ntg*4 + kt;
// lane l, byte j<16: B[n' = ntg*16 + (l&15)][k = kt*64 + (l>>4)*16 + j]
__global__ void k_prep2(const float* __restrict__ whh, uchar_t* __restrict__ whhI8) {
    int j = blockIdx.x * 256 + threadIdx.x;  // < 262144
    int f = j >> 10, r = j & 1023;
    int lane = r >> 4, jj = r & 15;
    int ntg = f >> 2, kt = f & 3;
    int np = ntg * 16 + (lane & 15);
    int k = kt * 64 + ((lane >> 4) << 4) + jj;
    int u = np >> 2, gg = np & 3;
    int qv = __float2int_rn(whh[(gg * 256 + u) * 256 + k] * 1024.f);
    qv = min(max(qv, -127), 127);
    whhI8[j] = (uchar_t)(qv & 0xFF);
}

// ---------------- graph kernel: one block per (b,s), fused transform MFMA -----------
__global__ __launch_bounds__(128) void k_graph(const void* __restrict__ inputs,
                                               const void* __restrict__ triples,
                                               const void* __restrict__ id2,
                                               const float* __restrict__ wordE,
                                               const float* __restrict__ entE,
                                               const ushort_t* __restrict__ Wb,
                                               const float* __restrict__ trelP,
                                               ushort_t* __restrict__ tfeat,
                                               const unsigned* __restrict__ dflag) {
    int di = ((*dflag) >> 1) & 1;
    int bs = blockIdx.x;
    int tid = threadIdx.x;
    __shared__ __align__(16) ushort_t As[32][256];  // [t][k]: head k<100, tail 128..227
    __shared__ int rids[32];
    __shared__ float e_sm[32];
    __shared__ float alpha[32];
    __shared__ int vflag;
    if (tid == 0) vflag = 0;
    __syncthreads();
    int t = tid >> 2, l4 = tid & 3;
    long long base3 = ((long long)bs * 32 + t) * 3;
    int hid = iacc(triples, base3, di);
    int tl = iacc(triples, base3 + 1, di);
    int rid = iacc(triples, base3 + 2, di);
    hid = min(max(hid, 0), NENT - 1);
    tl = min(max(tl, 0), NENT - 1);
    rid = min(max(rid, 0), NREL - 1);
    if (l4 == 0) {
        rids[t] = rid;
        if (iacc(id2, (long long)bs * 32 + t, di) != -1) vflag = 1;
    }
    for (int k = l4; k < 256; k += 4) {
        float v = 0.f;
        if (k < 100) v = entE[(long long)hid * 100 + k];
        else if (k >= 128 && k < 228) v = entE[(long long)tl * 100 + (k - 128)];
        As[t][k] = f2b(v);
    }
    __syncthreads();
    int wave = tid >> 6, lane = tid & 63, m16 = lane & 15, q = lane >> 4;
    f32x4 acc[7];
#pragma unroll
    for (int nt = 0; nt < 7; nt++) acc[nt] = {0.f, 0.f, 0.f, 0.f};
#pragma unroll
    for (int ks = 0; ks < 8; ++ks) {
        bf16x8 af = *reinterpret_cast<const bf16x8*>(&As[wave * 16 + m16][ks * 32 + q * 8]);
#pragma unroll
        for (int nt = 0; nt < 7; ++nt) {
            bf16x8 bf_ = *reinterpret_cast<const bf16x8*>(&Wb[(nt * 16 + m16) * 256 + ks * 32 + q * 8]);
            acc[nt] = __builtin_amdgcn_mfma_f32_16x16x32_bf16(af, bf_, acc[nt], 0, 0, 0);
        }
    }
#pragma unroll
    for (int rr = 0; rr < 4; ++rr) {
        int m = wave * 16 + q * 4 + rr;
        const float* tr = trelP + rids[m] * 112;
        float s = 0.f;
#pragma unroll
        for (int nt = 0; nt < 7; ++nt) s += tanhf(acc[nt][rr]) * tr[nt * 16 + m16];
        s += __shfl_xor(s, 1);
        s += __shfl_xor(s, 2);
        s += __shfl_xor(s, 4);
        s += __shfl_xor(s, 8);
        if (m16 == 0) e_sm[m] = s;
    }
    __syncthreads();
    if (tid < 32) {
        float v = e_sm[tid];
        float mx = v;
        for (int off = 16; off >= 1; off >>= 1) mx = fmaxf(mx, __shfl_xor(mx, off));
        float ex = __expf(v - mx);
        float sm = ex;
        for (int off = 16; off >= 1; off >>= 1) sm += __shfl_xor(sm, off);
        alpha[tid] = ex / sm;
    }
    __syncthreads();
    float scale = vflag ? 1.f : 0.f;
    long long row = (long long)bs * KPAD;
    for (int k = tid; k < 200; k += 128) {
        int kk = (k < 100) ? k : (k + 28);
        float ge = 0.f;
#pragma unroll 8
        for (int tt = 0; tt < 32; ++tt) ge += alpha[tt] * b2f(As[tt][kk]);
        tfeat[row + 300 + k] = f2b(ge * scale);
    }
    int w = iacc(inputs, bs, di);
    w = min(max(w, 0), NVOC - 1);
    for (int j = tid; j < 300; j += 128) tfeat[row + j] = f2b(wordE[(long long)w * 300 + j]);
    if (tid < 12) tfeat[row + 500 + tid] = 0;
}

// ---------------- GEMM: xw = tfeat @ w_ihT + b_ih + b_hh (bf16, gate-interleaved) ---
// store layout: xwB[i*1024 + (n&255)*4 + (n>>8)]  (unit-major, 4 gates adjacent)
__global__ __launch_bounds__(256) void k_gemm_xw(const ushort_t* __restrict__ A,
                                                 const ushort_t* __restrict__ Bm,
                                                 const float* __restrict__ bih,
                                                 const float* __restrict__ bhh,
                                                 ushort_t* __restrict__ xwB) {
    __shared__ __align__(16) ushort_t As[64 * 32];
    __shared__ __align__(16) ushort_t Bs[64 * 32];
    int tid = threadIdx.x;
    int i0 = blockIdx.x * 64, n0 = blockIdx.y * 64;
    int wave = tid >> 6, lane = tid & 63, m16 = lane & 15, q = lane >> 4;
    f32x4 acc[4];
#pragma unroll
    for (int t = 0; t < 4; t++) acc[t] = {0.f, 0.f, 0.f, 0.f};
    int r = tid >> 2, cq = (tid & 3) * 8;
    int kk = tid >> 3, nn = (tid & 7) * 8;
    for (int kt = 0; kt < 16; ++kt) {
        int k0 = kt * 32;
        {
            const ushort_t* src = A + (i0 + r) * 512 + k0 + cq;
            ushort4 v0 = *(const ushort4*)src;
            ushort4 v1 = *(const ushort4*)(src + 4);
            *(ushort4*)&As[r * 32 + cq] = v0;
            *(ushort4*)&As[r * 32 + cq + 4] = v1;
        }
        {
            const ushort_t* src = Bm + (k0 + kk) * 1024 + n0 + nn;
            ushort4 v0 = *(const ushort4*)(src);
            ushort4 v1 = *(const ushort4*)(src + 4);
            Bs[(nn + 0) * 32 + kk] = v0.x; Bs[(nn + 1) * 32 + kk] = v0.y;
            Bs[(nn + 2) * 32 + kk] = v0.z; Bs[(nn + 3) * 32 + kk] = v0.w;
            Bs[(nn + 4) * 32 + kk] = v1.x; Bs[(nn + 5) * 32 + kk] = v1.y;
            Bs[(nn + 6) * 32 + kk] = v1.z; Bs[(nn + 7) * 32 + kk] = v1.w;
        }
        __syncthreads();
        bf16x8 af = *reinterpret_cast<const bf16x8*>(&As[(wave * 16 + m16) * 32 + q * 8]);
#pragma unroll
        for (int t = 0; t < 4; t++) {
            bf16x8 bf_ = *reinterpret_cast<const bf16x8*>(&Bs[(t * 16 + m16) * 32 + q * 8]);
            acc[t] = __builtin_amdgcn_mfma_f32_16x16x32_bf16(af, bf_, acc[t], 0, 0, 0);
        }
        __syncthreads();
    }
#pragma unroll
    for (int t = 0; t < 4; t++) {
        int n = n0 + t * 16 + m16;
        float bias = bih[n] + bhh[n];
        int ni = ((n & 255) << 2) + (n >> 8);
#pragma unroll
        for (int rr = 0; rr < 4; rr++) {
            int i = i0 + wave * 16 + q * 4 + rr;
            xwB[i * 1024 + ni] = f2b(acc[t][rr] + bias);
        }
    }
}

// ---------------- LSTM scan: 64 blocks x 512 thr, ONE batch row/block, i8 MFMA ------
// w_hh (x1024, i8, gate-interleaved n'=u*4+g) register-resident: 8 waves x 8 ntg x
// 4 kt x 16B. Real data = row 0 only (q=0 lanes, reg 0) -> fanout via 4KB gbuf LDS
// (conflict-free b32 writes, one b128 read per cell). Phase B: 256 lanes x 1 cell.
// 2 lgkm-only barriers/step; hallB global stores never drained in-loop.
__global__ __launch_bounds__(512, 2) void k_lstm(const ushort_t* __restrict__ xwB,
                                                 const uchar_t* __restrict__ whhI8,
                                                 const void* __restrict__ lengths,
                                                 ushort_t* __restrict__ hallB,
                                                 const unsigned* __restrict__ dflag) {
    const int LDH = 272;  // hsm row stride bytes (non-pow2: staggers A-frag read banks)
    int di = ((*dflag) >> 1) & 1;
    int b = blockIdx.x;  // one batch row per block
    int tid = threadIdx.x;
    int wave = tid >> 6, lane = tid & 63;
    int c16 = lane & 15, q = lane >> 4;
    __shared__ __align__(16) uchar_t hsm[16 * 272];  // h*127 as i8; rows 1..15 stay 0
    __shared__ __align__(16) float gbuf[1024];       // gates_hh*(127*1024) as f32, [n']
    for (int j = tid; j < 16 * 272; j += 512) hsm[j] = 0;
    // register-resident weight fragments (once): wreg[i][kt] for ntg = wave*8+i
    i32x4 wreg[8][4];
    {
        const uchar_t* wp = whhI8 + (((long long)(wave * 8) * 4) * 64 + lane) * 16;
#pragma unroll
        for (int i = 0; i < 8; ++i)
#pragma unroll
            for (int kt = 0; kt < 4; ++kt)
                wreg[i][kt] = *(const i32x4*)(wp + (((i << 2) + kt) << 10));
    }
    int len = iacc(lengths, b, di);
    int u = tid;  // cell unit for tid<256
    float cc = 0.f;
    const float S = 1.f / (127.f * 1024.f);
    long long xbase = ((long long)(b * 128) << 10) + ((long long)u << 2);
    ushort4 xv = {0, 0, 0, 0}, xn;
    if (tid < 256) xv = *(const ushort4*)(xwB + xbase);
    __syncthreads();
    for (int s = 0; s < 128; ++s) {
        // phase A operands: h row-slab (A-frag: row=c16, k = kt*64 + q*16 + j)
        const uchar_t* hb = &hsm[c16 * LDH];
        i32x4 afr[4];
#pragma unroll
        for (int kt = 0; kt < 4; ++kt)
            afr[kt] = *(const i32x4*)(hb + kt * 64 + q * 16);
        // prefetch next step's xw early (before any stores this step)
        int sn = (s < 127) ? s + 1 : 127;
        if (tid < 256) xn = *(const ushort4*)(xwB + xbase + ((long long)sn << 10));
#pragma unroll
        for (int i = 0; i < 8; ++i) {
            i32x4 a = {0, 0, 0, 0};
#pragma unroll
            for (int kt = 0; kt < 4; ++kt)
                a = __builtin_amdgcn_mfma_i32_16x16x64_i8(afr[kt], wreg[i][kt], a, 0, 0, 0);
            if (q == 0) gbuf[(wave * 8 + i) * 16 + c16] = (float)a[0];  // row 0 only
        }
        asm volatile("s_waitcnt lgkmcnt(0)\n\ts_barrier" ::: "memory");
        if (tid < 256) {
            f32x4 gv = *(const f32x4*)&gbuf[u * 4];  // gates i,f,g,o of unit u
            float iv = b2f(xv.x) + gv[0] * S;
            float fv = b2f(xv.y) + gv[1] * S;
            float gg = b2f(xv.z) + gv[2] * S;
            float ov = b2f(xv.w) + gv[3] * S;
            float c = sigm(fv) * cc + sigm(iv) * tanh_fast(gg);
            float h = sigm(ov) * tanh_fast(c);
            cc = c;
            hsm[u] = (uchar_t)(__float2int_rn(h * 127.f) & 0xFF);
            hallB[((long long)(b * 128 + s) << 8) + u] = (s < len) ? f2b(h) : (ushort_t)0;
            xv = xn;
        }
        asm volatile("s_waitcnt lgkmcnt(0)\n\ts_barrier" ::: "memory");
    }
}

// ---------------- attention + classifier head (f32 out) -----------------------------
__global__ __launch_bounds__(256) void k_att(const ushort_t* __restrict__ hallB,
                                             const float* __restrict__ Watt,
                                             const float* __restrict__ batt,
                                             const float* __restrict__ Wout,
                                             const float* __restrict__ bout,
                                             float* __restrict__ out) {
    int b = blockIdx.x, tid = threadIdx.x;
    __shared__ float waf[256], lg[128], msk[128], ps[128], enc[256], o3[3], red[1];
    waf[tid] = Watt[tid];
    __syncthreads();
    int s = tid >> 1, half = tid & 1;
    const ushort_t* hb = hallB + (b * 128 + s) * 256 + half * 128;
    float part = 0.f;
    for (int j = 0; j < 128; ++j) part += b2f(hb[j]) * waf[half * 128 + j];
    part += __shfl_xor(part, 1);
    if (half == 0) lg[s] = part + batt[0];
    __syncthreads();
    if (tid < 128) {
        float lv = lg[tid];
        float m = (lv != 0.f) ? 1.f : 0.f;
        msk[tid] = m;
        lg[tid] = lv * m;
    }
    __syncthreads();
    if (tid == 0) {
        float mx = -1e30f;
        for (int i = 0; i < 128; ++i) mx = fmaxf(mx, lg[i]);
        red[0] = mx;
    }
    __syncthreads();
    if (tid < 128) ps[tid] = __expf(lg[tid] - red[0]);
    __syncthreads();
    if (tid == 0) {
        float sm = 0.f;
        for (int i = 0; i < 128; ++i) sm += ps[i];
        red[0] = sm;
    }
    __syncthreads();
    if (tid < 128) ps[tid] = ps[tid] / red[0] * msk[tid];
    __syncthreads();
    if (tid == 0) {
        float sm = 0.f;
        for (int i = 0; i < 128; ++i) sm += ps[i];
        red[0] = sm + 1e-13f;
    }
    __syncthreads();
    if (tid < 128) {
        float p = ps[tid] / red[0];
        ps[tid] = p;
        out[192 + b * 128 + tid] = p;
    }
    __syncthreads();
    {
        float ej = 0.f;
        for (int ss = 0; ss < 128; ++ss) ej += ps[ss] * b2f(hallB[(b * 128 + ss) * 256 + tid]);
        enc[tid] = ej;
    }
    __syncthreads();
    if (tid < 3) {
        float a = 0.f;
        for (int j = 0; j < 256; ++j) a += enc[j] * Wout[tid * 256 + j];
        o3[tid] = a + bout[tid];
    }
    __syncthreads();
    if (tid == 0) {
        float m = fmaxf(o3[0], fmaxf(o3[1], o3[2]));
        float l = logf(__expf(o3[0] - m) + __expf(o3[1] - m) + __expf(o3[2] - m)) + m;
        out[b * 3 + 0] = o3[0] - l;
        out[b * 3 + 1] = o3[1] - l;
        out[b * 3 + 2] = o3[2] - l;
    }
}

extern "C" void kernel_launch(void* const* d_in, const int* in_sizes, int n_in,
                              void* d_out, int out_size, void* d_ws, size_t ws_size,
                              hipStream_t stream) {
    float* out = (float*)d_out;
    static const long long EXP[16] = {8192, 786432, 64, 262144, 15000000, 20000000,
                                      50000, 20000, 512000, 262144, 1024, 1024,
                                      256, 1, 768, 3};
    int ob = (out_size + 255) / 256;
    if (n_in != 16 || out_size != 8384) {
        hipLaunchKernelGGL(k_sentinel, dim3(ob), dim3(256), 0, stream, out, out_size, -8192.f);
        return;
    }
    for (int i = 0; i < 16; ++i) {
        if ((long long)in_sizes[i] != EXP[i]) {
            hipLaunchKernelGGL(k_sentinel, dim3(ob), dim3(256), 0, stream, out, out_size,
                               -(4096.f + 32.f * i));
            return;
        }
    }

    const void* inputs = d_in[0];
    const void* triples = d_in[1];
    const void* lengths = d_in[2];
    const void* id2 = d_in[3];
    const float* wordE = (const float*)d_in[4];
    const float* entE = (const float*)d_in[5];
    const float* relE = (const float*)d_in[6];
    const float* Went = (const float*)d_in[7];
    const float* wih = (const float*)d_in[8];
    const float* whh = (const float*)d_in[9];
    const float* bih = (const float*)d_in[10];
    const float* bhh = (const float*)d_in[11];
    const float* Watt = (const float*)d_in[12];
    const float* batt = (const float*)d_in[13];
    const float* Wout = (const float*)d_in[14];
    const float* bout = (const float*)d_in[15];
    char* ws = (char*)d_ws;

    // workspace layout — total 26,496,000 B (< proven 27,028,224)
    constexpr size_t OFF_XW = 0;            // ushort 8192*1024*2 = 16,777,216
    constexpr size_t OFF_TFEAT = 16777216;  // ushort 8192*512*2 = 8,388,608 (hallB overlays)
    constexpr size_t OFF_WIHT = 25165824;   // ushort 512*1024*2 = 1,048,576 (whhI8 overlays after gemm)
    constexpr size_t OFF_WB = 26214400;     // ushort 112*256*2 = 57,344
    constexpr size_t OFF_FLAGS = 26271744;  // u32 dflag
    constexpr size_t OFF_TRELP = 26272000;  // float 500*112*4 = 224,000 -> end 26,496,000
    constexpr size_t WS_NEEDED = 26496000;

    if (ws_size < WS_NEEDED) {
        hipLaunchKernelGGL(k_sentinel, dim3(ob), dim3(256), 0, stream, out, out_size,
                           -(float)(ws_size >> 20));
        return;
    }

    ushort_t* xwB = (ushort_t*)(ws + OFF_XW);
    ushort_t* tfeat = (ushort_t*)(ws + OFF_TFEAT);
    ushort_t* hallB = (ushort_t*)(ws + OFF_TFEAT);  // overlays tfeat after k_gemm_xw
    ushort_t* wihT = (ushort_t*)(ws + OFF_WIHT);
    uchar_t* whhI8 = (uchar_t*)(ws + OFF_WIHT);     // overlays wihT after k_gemm_xw
    ushort_t* Wb = (ushort_t*)(ws + OFF_WB);
    unsigned* dflag = (unsigned*)(ws + OFF_FLAGS);
    float* trelP = (float*)(ws + OFF_TRELP);

    hipLaunchKernelGGL(k_det, dim3(1), dim3(256), 0, stream, (const int*)triples, dflag);
    hipLaunchKernelGGL(k_prep, dim3(2048), dim3(256), 0, stream,
                       Went, wih, relE, Wb, wihT, trelP);
    hipLaunchKernelGGL(k_graph, dim3(8192), dim3(128), 0, stream,
                       inputs, triples, id2, wordE, entE, Wb, trelP, tfeat, dflag);
    hipLaunchKernelGGL(k_gemm_xw, dim3(128, 16), dim3(256), 0, stream,
                       tfeat, wihT, bih, bhh, xwB);
    hipLaunchKernelGGL(k_prep2, dim3(1024), dim3(256), 0, stream, whh, whhI8);
    hipLaunchKernelGGL(k_lstm, dim3(64), dim3(512), 0, stream, xwB, whhI8, lengths, hallB, dflag);
    hipLaunchKernelGGL(k_att, dim3(64), dim3(256), 0, stream, hallB, Watt, batt, Wout, bout, out);
}

// Round 5
// 508.812 us; speedup vs baseline: 1.4666x; 1.0834x over previous
//
#include <hip/hip_runtime.h>

// RNNSequenceClassifier on MI355X. Inputs/outputs are FLOAT32 (proven R4/R5).
// prep -> graph/t_feat (coalesced wave-gather + swizzled LDS + fused transform MFMA)
// -> xw GEMM (MFMA, gate-interleaved bf16 out) -> prep2 (whh -> i8 MFMA B-frags)
// -> i8-MFMA LSTM scan (64 blocks x 1 row, weights register-resident) -> attention/head.

typedef unsigned short ushort_t;
typedef unsigned char uchar_t;
typedef __bf16 bf16x8 __attribute__((ext_vector_type(8)));
typedef float f32x4 __attribute__((ext_vector_type(4)));
typedef int i32x4 __attribute__((ext_vector_type(4)));

#define NENT 200000
#define NVOC 50000
#define NREL 500
#define KPAD 512
// swizzled byte offset into As[32][256] bf16: spreads b128 A-frag reads across all
// 8 16B-bank-groups (was 16-lanes-on-4-groups) and keeps stores conflict-free.
#define ASW(t, k) ((((t) * 512 + (k) * 2)) ^ (((t) & 7) << 4))

__device__ __forceinline__ float b2f(ushort_t u) {
    return __uint_as_float(((unsigned)u) << 16);
}
__device__ __forceinline__ ushort_t f2b(float f) {
    unsigned u = __float_as_uint(f);
    unsigned r = (u + 0x7FFFu + ((u >> 16) & 1u)) >> 16;
    return (ushort_t)r;
}
__device__ __forceinline__ float sigm(float x) {
    return __builtin_amdgcn_rcpf(1.f + __expf(-x));
}
__device__ __forceinline__ float tanh_fast(float x) {
    float xx = fminf(fmaxf(x, -15.f), 15.f);
    float t = __expf(2.f * xx);
    return 1.f - 2.f * __builtin_amdgcn_rcpf(t + 1.f);
}
// adaptive int read: int32 (di==0) or int64-low-word (di==1)
__device__ __forceinline__ int iacc(const void* p, long long i, int di) {
    return di ? ((const int*)p)[2 * i] : ((const int*)p)[i];
}

// ---------------- sentinel (f32 out) ------------------------------------------------
__global__ void k_sentinel(float* __restrict__ out, int n, float val) {
    int i = blockIdx.x * 256 + threadIdx.x;
    if (i < n) out[i] = val;
}

// ---------------- tiny int-dtype probe ----------------------------------------------
__global__ void k_det(const int* __restrict__ triples, unsigned* __restrict__ dflag) {
    __shared__ int cnt;
    int tid = threadIdx.x;
    if (tid == 0) cnt = 0;
    __syncthreads();
    int nz = 0;
    for (int i = tid; i < 1500; i += 256)
        if (triples[2 * i + 1] != 0) nz++;
    if (nz) atomicAdd(&cnt, nz);
    __syncthreads();
    if (tid == 0) *dflag = (cnt == 0) ? 2u : 0u;  // bit1: ints are i64
}

// ---------------- prep: Wb[112][256], trelP[500][112], wihT[512][1024] --------------
__global__ void k_prep(const float* __restrict__ Went, const float* __restrict__ wih,
                       const float* __restrict__ relE,
                       ushort_t* __restrict__ Wb, ushort_t* __restrict__ wihT,
                       float* __restrict__ trelP) {
    int i = blockIdx.x * 256 + threadIdx.x;
    int stride = gridDim.x * 256;
    if (i < 112 * 256) {
        int n = i >> 8, k = i & 255;
        float v = 0.f;
        if (n < 100) {
            if (k < 100) v = Went[n * 200 + k];
            else if (k >= 128 && k < 228) v = Went[n * 200 + 100 + (k - 128)];
        }
        Wb[i] = f2b(v);
    }
    for (int j = i; j < 500 * 128; j += stride) {
        int r_ = j >> 7, d = j & 127;
        if (d < 112) trelP[r_ * 112 + d] = (d < 100) ? tanhf(relE[r_ * 100 + d]) : 0.f;
    }
    for (int j = i; j < 512 * 1024; j += stride) {
        int k = j >> 10, n = j & 1023;
        wihT[j] = (k < 500) ? f2b(wih[(long long)n * 500 + k]) : (ushort_t)0;
    }
}

// ---------------- prep2: whhI8 = rint(1024*w_hh) as i8 in MFMA B-fragment order -----
// gate-interleaved n' = u*4 + g  (orig row n = g*256 + u), frag f = ntg*4 + kt;
// lane l, byte j<16: B[n' = ntg*16 + (l&15)][k = kt*64 + (l>>4)*16 + j]
__global__ void k_prep2(const float* __restrict__ whh, uchar_t* __restrict__ whhI8) {
    int j = blockIdx.x * 256 + threadIdx.x;  // < 262144
    int f = j >> 10, r = j & 1023;
    int lane = r >> 4, jj = r & 15;
    int ntg = f >> 2, kt = f & 3;
    int np = ntg * 16 + (lane & 15);
    int k = kt * 64 + ((lane >> 4) << 4) + jj;
    int u = np >> 2, gg = np & 3;
    int qv = __float2int_rn(whh[(gg * 256 + u) * 256 + k] * 1024.f);
    qv = min(max(qv, -127), 127);
    whhI8[j] = (uchar_t)(qv & 0xFF);
}

// ---------------- graph kernel: one block per (b,s), fused transform MFMA -----------
// entity gather: one row per wave-iter, float2 per lane (coalesced 400B); As swizzled.
__global__ __launch_bounds__(128) void k_graph(const void* __restrict__ inputs,
                                               const void* __restrict__ triples,
                                               const void* __restrict__ id2,
                                               const float* __restrict__ wordE,
                                               const float* __restrict__ entE,
                                               const ushort_t* __restrict__ Wb,
                                               const float* __restrict__ trelP,
                                               ushort_t* __restrict__ tfeat,
                                               const unsigned* __restrict__ dflag) {
    int di = ((*dflag) >> 1) & 1;
    int bs = blockIdx.x;
    int tid = threadIdx.x;
    __shared__ __align__(16) uchar_t As[32 * 512];  // swizzled [t][k] bf16
    __shared__ int hid_sm[32], tl_sm[32], rids[32];
    __shared__ float e_sm[32], alpha[32];
    __shared__ int vflag;
    int wave = tid >> 6, lane = tid & 63;

    if (wave == 0) {
        // triple ids + vflag via ballot (wave-0 only: no init race)
        int idv = -1;
        if (lane < 32) {
            long long base3 = ((long long)bs * 32 + lane) * 3;
            hid_sm[lane] = min(max(iacc(triples, base3, di), 0), NENT - 1);
            tl_sm[lane] = min(max(iacc(triples, base3 + 1, di), 0), NENT - 1);
            rids[lane] = min(max(iacc(triples, base3 + 2, di), 0), NREL - 1);
            idv = iacc(id2, (long long)bs * 32 + lane, di);
        }
        unsigned long long bal = __ballot(idv != -1);
        if (lane == 0) vflag = (bal != 0ULL) ? 1 : 0;
    } else {
        // zero pad columns 100..127 and 228..255 (8B stores, swizzle-safe)
        for (int j = lane; j < 32 * 14; j += 64) {
            int t = j / 14, g = j % 14;
            int c = (g < 7) ? (100 + g * 4) : (228 + (g - 7) * 4);
            *(unsigned long long*)&As[ASW(t, c)] = 0ULL;
        }
    }
    __syncthreads();
    // coalesced entity gather: slot<32 = head row t (cols 0..99), else tail (128..227)
#pragma unroll 4
    for (int slot = wave; slot < 64; slot += 2) {
        int t = slot & 31;
        const float* src = entE + (long long)((slot < 32) ? hid_sm[t] : tl_sm[t]) * 100;
        int cb = (slot < 32) ? 0 : 128;
        if (lane < 50) {
            float2 v = *(const float2*)(src + 2 * lane);
            unsigned pk = ((unsigned)f2b(v.y) << 16) | (unsigned)f2b(v.x);
            *(unsigned*)&As[ASW(t, cb + 2 * lane)] = pk;
        }
    }
    __syncthreads();
    int m16 = lane & 15, q = lane >> 4;
    f32x4 acc[7];
#pragma unroll
    for (int nt = 0; nt < 7; nt++) acc[nt] = {0.f, 0.f, 0.f, 0.f};
#pragma unroll
    for (int ks = 0; ks < 8; ++ks) {
        bf16x8 af = *reinterpret_cast<const bf16x8*>(&As[ASW(wave * 16 + m16, ks * 32 + q * 8)]);
#pragma unroll
        for (int nt = 0; nt < 7; ++nt) {
            bf16x8 bf_ = *reinterpret_cast<const bf16x8*>(&Wb[(nt * 16 + m16) * 256 + ks * 32 + q * 8]);
            acc[nt] = __builtin_amdgcn_mfma_f32_16x16x32_bf16(af, bf_, acc[nt], 0, 0, 0);
        }
    }
#pragma unroll
    for (int rr = 0; rr < 4; ++rr) {
        int m = wave * 16 + q * 4 + rr;
        const float* tr = trelP + rids[m] * 112;
        float s = 0.f;
#pragma unroll
        for (int nt = 0; nt < 7; ++nt) s += tanh_fast(acc[nt][rr]) * tr[nt * 16 + m16];
        s += __shfl_xor(s, 1);
        s += __shfl_xor(s, 2);
        s += __shfl_xor(s, 4);
        s += __shfl_xor(s, 8);
        if (m16 == 0) e_sm[m] = s;
    }
    __syncthreads();
    if (tid < 32) {
        float v = e_sm[tid];
        float mx = v;
        for (int off = 16; off >= 1; off >>= 1) mx = fmaxf(mx, __shfl_xor(mx, off));
        float ex = __expf(v - mx);
        float sm = ex;
        for (int off = 16; off >= 1; off >>= 1) sm += __shfl_xor(sm, off);
        alpha[tid] = ex / sm;
    }
    __syncthreads();
    float scale = vflag ? 1.f : 0.f;
    long long row = (long long)bs * KPAD;
    for (int k = tid; k < 200; k += 128) {
        int kk = (k < 100) ? k : (k + 28);
        float ge = 0.f;
#pragma unroll 8
        for (int tt = 0; tt < 32; ++tt)
            ge += alpha[tt] * b2f(*(const ushort_t*)&As[ASW(tt, kk)]);
        tfeat[row + 300 + k] = f2b(ge * scale);
    }
    int w = min(max(iacc(inputs, bs, di), 0), NVOC - 1);
    const float* wsrc = wordE + (long long)w * 300;
    for (int j = tid; j < 150; j += 128) {
        float2 v = *(const float2*)(wsrc + 2 * j);
        *(unsigned*)&tfeat[row + 2 * j] = ((unsigned)f2b(v.y) << 16) | (unsigned)f2b(v.x);
    }
    if (tid < 12) tfeat[row + 500 + tid] = 0;
}

// ---------------- GEMM: xw = tfeat @ w_ihT + b_ih + b_hh (bf16, gate-interleaved) ---
// store layout: xwB[i*1024 + (n&255)*4 + (n>>8)]  (unit-major, 4 gates adjacent)
__global__ __launch_bounds__(256) void k_gemm_xw(const ushort_t* __restrict__ A,
                                                 const ushort_t* __restrict__ Bm,
                                                 const float* __restrict__ bih,
                                                 const float* __restrict__ bhh,
                                                 ushort_t* __restrict__ xwB) {
    __shared__ __align__(16) ushort_t As[64 * 32];
    __shared__ __align__(16) ushort_t Bs[64 * 32];
    int tid = threadIdx.x;
    int i0 = blockIdx.x * 64, n0 = blockIdx.y * 64;
    int wave = tid >> 6, lane = tid & 63, m16 = lane & 15, q = lane >> 4;
    f32x4 acc[4];
#pragma unroll
    for (int t = 0; t < 4; t++) acc[t] = {0.f, 0.f, 0.f, 0.f};
    int r = tid >> 2, cq = (tid & 3) * 8;
    int kk = tid >> 3, nn = (tid & 7) * 8;
    for (int kt = 0; kt < 16; ++kt) {
        int k0 = kt * 32;
        {
            const ushort_t* src = A + (i0 + r) * 512 + k0 + cq;
            ushort4 v0 = *(const ushort4*)src;
            ushort4 v1 = *(const ushort4*)(src + 4);
            *(ushort4*)&As[r * 32 + cq] = v0;
            *(ushort4*)&As[r * 32 + cq + 4] = v1;
        }
        {
            const ushort_t* src = Bm + (k0 + kk) * 1024 + n0 + nn;
            ushort4 v0 = *(const ushort4*)(src);
            ushort4 v1 = *(const ushort4*)(src + 4);
            Bs[(nn + 0) * 32 + kk] = v0.x; Bs[(nn + 1) * 32 + kk] = v0.y;
            Bs[(nn + 2) * 32 + kk] = v0.z; Bs[(nn + 3) * 32 + kk] = v0.w;
            Bs[(nn + 4) * 32 + kk] = v1.x; Bs[(nn + 5) * 32 + kk] = v1.y;
            Bs[(nn + 6) * 32 + kk] = v1.z; Bs[(nn + 7) * 32 + kk] = v1.w;
        }
        __syncthreads();
        bf16x8 af = *reinterpret_cast<const bf16x8*>(&As[(wave * 16 + m16) * 32 + q * 8]);
#pragma unroll
        for (int t = 0; t < 4; t++) {
            bf16x8 bf_ = *reinterpret_cast<const bf16x8*>(&Bs[(t * 16 + m16) * 32 + q * 8]);
            acc[t] = __builtin_amdgcn_mfma_f32_16x16x32_bf16(af, bf_, acc[t], 0, 0, 0);
        }
        __syncthreads();
    }
#pragma unroll
    for (int t = 0; t < 4; t++) {
        int n = n0 + t * 16 + m16;
        float bias = bih[n] + bhh[n];
        int ni = ((n & 255) << 2) + (n >> 8);
#pragma unroll
        for (int rr = 0; rr < 4; rr++) {
            int i = i0 + wave * 16 + q * 4 + rr;
            xwB[i * 1024 + ni] = f2b(acc[t][rr] + bias);
        }
    }
}

// ---------------- LSTM scan: 64 blocks x 512 thr, ONE batch row/block, i8 MFMA ------
// w_hh (x1024, i8, gate-interleaved n'=u*4+g) register-resident: 8 waves x 8 ntg x
// 4 kt x 16B. Real data = row 0 only (q=0 lanes, reg 0) -> fanout via 4KB gbuf LDS
// (conflict-free b32 writes, one b128 read per cell). Phase B: 256 lanes x 1 cell.
// 2 lgkm-only barriers/step; hallB global stores never drained in-loop.
__global__ __launch_bounds__(512, 2) void k_lstm(const ushort_t* __restrict__ xwB,
                                                 const uchar_t* __restrict__ whhI8,
                                                 const void* __restrict__ lengths,
                                                 ushort_t* __restrict__ hallB,
                                                 const unsigned* __restrict__ dflag) {
    const int LDH = 272;  // hsm row stride bytes (non-pow2: staggers A-frag read banks)
    int di = ((*dflag) >> 1) & 1;
    int b = blockIdx.x;  // one batch row per block
    int tid = threadIdx.x;
    int wave = tid >> 6, lane = tid & 63;
    int c16 = lane & 15, q = lane >> 4;
    __shared__ __align__(16) uchar_t hsm[16 * 272];  // h*127 as i8; rows 1..15 stay 0
    __shared__ __align__(16) float gbuf[1024];       // gates_hh*(127*1024) as f32, [n']
    for (int j = tid; j < 16 * 272; j += 512) hsm[j] = 0;
    // register-resident weight fragments (once): wreg[i][kt] for ntg = wave*8+i
    i32x4 wreg[8][4];
    {
        const uchar_t* wp = whhI8 + (((long long)(wave * 8) * 4) * 64 + lane) * 16;
#pragma unroll
        for (int i = 0; i < 8; ++i)
#pragma unroll
            for (int kt = 0; kt < 4; ++kt)
                wreg[i][kt] = *(const i32x4*)(wp + (((i << 2) + kt) << 10));
    }
    int len = iacc(lengths, b, di);
    int u = tid;  // cell unit for tid<256
    float cc = 0.f;
    const float S = 1.f / (127.f * 1024.f);
    long long xbase = ((long long)(b * 128) << 10) + ((long long)u << 2);
    ushort4 xv = {0, 0, 0, 0}, xn;
    if (tid < 256) xv = *(const ushort4*)(xwB + xbase);
    __syncthreads();
    for (int s = 0; s < 128; ++s) {
        // phase A operands: h row-slab (A-frag: row=c16, k = kt*64 + q*16 + j)
        const uchar_t* hb = &hsm[c16 * LDH];
        i32x4 afr[4];
#pragma unroll
        for (int kt = 0; kt < 4; ++kt)
            afr[kt] = *(const i32x4*)(hb + kt * 64 + q * 16);
        // prefetch next step's xw early (before any stores this step)
        int sn = (s < 127) ? s + 1 : 127;
        if (tid < 256) xn = *(const ushort4*)(xwB + xbase + ((long long)sn << 10));
#pragma unroll
        for (int i = 0; i < 8; ++i) {
            i32x4 a = {0, 0, 0, 0};
#pragma unroll
            for (int kt = 0; kt < 4; ++kt)
                a = __builtin_amdgcn_mfma_i32_16x16x64_i8(afr[kt], wreg[i][kt], a, 0, 0, 0);
            if (q == 0) gbuf[(wave * 8 + i) * 16 + c16] = (float)a[0];  // row 0 only
        }
        asm volatile("s_waitcnt lgkmcnt(0)\n\ts_barrier" ::: "memory");
        if (tid < 256) {
            f32x4 gv = *(const f32x4*)&gbuf[u * 4];  // gates i,f,g,o of unit u
            float iv = b2f(xv.x) + gv[0] * S;
            float fv = b2f(xv.y) + gv[1] * S;
            float gg = b2f(xv.z) + gv[2] * S;
            float ov = b2f(xv.w) + gv[3] * S;
            float c = sigm(fv) * cc + sigm(iv) * tanh_fast(gg);
            float h = sigm(ov) * tanh_fast(c);
            cc = c;
            hsm[u] = (uchar_t)(__float2int_rn(h * 127.f) & 0xFF);
            hallB[((long long)(b * 128 + s) << 8) + u] = (s < len) ? f2b(h) : (ushort_t)0;
            xv = xn;
        }
        asm volatile("s_waitcnt lgkmcnt(0)\n\ts_barrier" ::: "memory");
    }
}

// ---------------- attention + classifier head (f32 out) -----------------------------
__global__ __launch_bounds__(256) void k_att(const ushort_t* __restrict__ hallB,
                                             const float* __restrict__ Watt,
                                             const float* __restrict__ batt,
                                             const float* __restrict__ Wout,
                                             const float* __restrict__ bout,
                                             float* __restrict__ out) {
    int b = blockIdx.x, tid = threadIdx.x;
    __shared__ float waf[256], lg[128], msk[128], ps[128], enc[256], o3[3], red[1];
    waf[tid] = Watt[tid];
    __syncthreads();
    int s = tid >> 1, half = tid & 1;
    const ushort_t* hb = hallB + (b * 128 + s) * 256 + half * 128;
    float part = 0.f;
    for (int j = 0; j < 128; ++j) part += b2f(hb[j]) * waf[half * 128 + j];
    part += __shfl_xor(part, 1);
    if (half == 0) lg[s] = part + batt[0];
    __syncthreads();
    if (tid < 128) {
        float lv = lg[tid];
        float m = (lv != 0.f) ? 1.f : 0.f;
        msk[tid] = m;
        lg[tid] = lv * m;
    }
    __syncthreads();
    if (tid == 0) {
        float mx = -1e30f;
        for (int i = 0; i < 128; ++i) mx = fmaxf(mx, lg[i]);
        red[0] = mx;
    }
    __syncthreads();
    if (tid < 128) ps[tid] = __expf(lg[tid] - red[0]);
    __syncthreads();
    if (tid == 0) {
        float sm = 0.f;
        for (int i = 0; i < 128; ++i) sm += ps[i];
        red[0] = sm;
    }
    __syncthreads();
    if (tid < 128) ps[tid] = ps[tid] / red[0] * msk[tid];
    __syncthreads();
    if (tid == 0) {
        float sm = 0.f;
        for (int i = 0; i < 128; ++i) sm += ps[i];
        red[0] = sm + 1e-13f;
    }
    __syncthreads();
    if (tid < 128) {
        float p = ps[tid] / red[0];
        ps[tid] = p;
        out[192 + b * 128 + tid] = p;
    }
    __syncthreads();
    {
        float ej = 0.f;
        for (int ss = 0; ss < 128; ++ss) ej += ps[ss] * b2f(hallB[(b * 128 + ss) * 256 + tid]);
        enc[tid] = ej;
    }
    __syncthreads();
    if (tid < 3) {
        float a = 0.f;
        for (int j = 0; j < 256; ++j) a += enc[j] * Wout[tid * 256 + j];
        o3[tid] = a + bout[tid];
    }
    __syncthreads();
    if (tid == 0) {
        float m = fmaxf(o3[0], fmaxf(o3[1], o3[2]));
        float l = logf(__expf(o3[0] - m) + __expf(o3[1] - m) + __expf(o3[2] - m)) + m;
        out[b * 3 + 0] = o3[0] - l;
        out[b * 3 + 1] = o3[1] - l;
        out[b * 3 + 2] = o3[2] - l;
    }
}

extern "C" void kernel_launch(void* const* d_in, const int* in_sizes, int n_in,
                              void* d_out, int out_size, void* d_ws, size_t ws_size,
                              hipStream_t stream) {
    float* out = (float*)d_out;
    static const long long EXP[16] = {8192, 786432, 64, 262144, 15000000, 20000000,
                                      50000, 20000, 512000, 262144, 1024, 1024,
                                      256, 1, 768, 3};
    int ob = (out_size + 255) / 256;
    if (n_in != 16 || out_size != 8384) {
        hipLaunchKernelGGL(k_sentinel, dim3(ob), dim3(256), 0, stream, out, out_size, -8192.f);
        return;
    }
    for (int i = 0; i < 16; ++i) {
        if ((long long)in_sizes[i] != EXP[i]) {
            hipLaunchKernelGGL(k_sentinel, dim3(ob), dim3(256), 0, stream, out, out_size,
                               -(4096.f + 32.f * i));
            return;
        }
    }

    const void* inputs = d_in[0];
    const void* triples = d_in[1];
    const void* lengths = d_in[2];
    const void* id2 = d_in[3];
    const float* wordE = (const float*)d_in[4];
    const float* entE = (const float*)d_in[5];
    const float* relE = (const float*)d_in[6];
    const float* Went = (const float*)d_in[7];
    const float* wih = (const float*)d_in[8];
    const float* whh = (const float*)d_in[9];
    const float* bih = (const float*)d_in[10];
    const float* bhh = (const float*)d_in[11];
    const float* Watt = (const float*)d_in[12];
    const float* batt = (const float*)d_in[13];
    const float* Wout = (const float*)d_in[14];
    const float* bout = (const float*)d_in[15];
    char* ws = (char*)d_ws;

    // workspace layout — total 26,496,000 B (< proven 27,028,224)
    constexpr size_t OFF_XW = 0;            // ushort 8192*1024*2 = 16,777,216
    constexpr size_t OFF_TFEAT = 16777216;  // ushort 8192*512*2 = 8,388,608 (hallB overlays)
    constexpr size_t OFF_WIHT = 25165824;   // ushort 512*1024*2 = 1,048,576 (whhI8 overlays after gemm)
    constexpr size_t OFF_WB = 26214400;     // ushort 112*256*2 = 57,344
    constexpr size_t OFF_FLAGS = 26271744;  // u32 dflag
    constexpr size_t OFF_TRELP = 26272000;  // float 500*112*4 = 224,000 -> end 26,496,000
    constexpr size_t WS_NEEDED = 26496000;

    if (ws_size < WS_NEEDED) {
        hipLaunchKernelGGL(k_sentinel, dim3(ob), dim3(256), 0, stream, out, out_size,
                           -(float)(ws_size >> 20));
        return;
    }

    ushort_t* xwB = (ushort_t*)(ws + OFF_XW);
    ushort_t* tfeat = (ushort_t*)(ws + OFF_TFEAT);
    ushort_t* hallB = (ushort_t*)(ws + OFF_TFEAT);  // overlays tfeat after k_gemm_xw
    ushort_t* wihT = (ushort_t*)(ws + OFF_WIHT);
    uchar_t* whhI8 = (uchar_t*)(ws + OFF_WIHT);     // overlays wihT after k_gemm_xw
    ushort_t* Wb = (ushort_t*)(ws + OFF_WB);
    unsigned* dflag = (unsigned*)(ws + OFF_FLAGS);
    float* trelP = (float*)(ws + OFF_TRELP);

    hipLaunchKernelGGL(k_det, dim3(1), dim3(256), 0, stream, (const int*)triples, dflag);
    hipLaunchKernelGGL(k_prep, dim3(2048), dim3(256), 0, stream,
                       Went, wih, relE, Wb, wihT, trelP);
    hipLaunchKernelGGL(k_graph, dim3(8192), dim3(128), 0, stream,
                       inputs, triples, id2, wordE, entE, Wb, trelP, tfeat, dflag);
    hipLaunchKernelGGL(k_gemm_xw, dim3(128, 16), dim3(256), 0, stream,
                       tfeat, wihT, bih, bhh, xwB);
    hipLaunchKernelGGL(k_prep2, dim3(1024), dim3(256), 0, stream, whh, whhI8);
    hipLaunchKernelGGL(k_lstm, dim3(64), dim3(512), 0, stream, xwB, whhI8, lengths, hallB, dflag);
    hipLaunchKernelGGL(k_att, dim3(64), dim3(256), 0, stream, hallB, Watt, batt, Wout, bout, out);
}

// Round 6
// 493.941 us; speedup vs baseline: 1.5107x; 1.0301x over previous
//
#include <hip/hip_runtime.h>

// RNNSequenceClassifier on MI355X. Inputs/outputs are FLOAT32 (proven R4/R5).
// prep -> graph/t_feat (256-thr blocks: 100% occupancy gather + swizzled LDS + fused
// transform MFMA) -> xw GEMM (MFMA, gate-interleaved bf16 out) -> prep2 (whh -> i8
// MFMA B-frags) -> i8-MFMA LSTM scan (64 blocks x 1 row, weights register-resident)
// -> attention/head.

typedef unsigned short ushort_t;
typedef unsigned char uchar_t;
typedef __bf16 bf16x8 __attribute__((ext_vector_type(8)));
typedef float f32x4 __attribute__((ext_vector_type(4)));
typedef int i32x4 __attribute__((ext_vector_type(4)));

#define NENT 200000
#define NVOC 50000
#define NREL 500
#define KPAD 512
// swizzled byte offset into As[32][256] bf16: spreads b128 A-frag reads across all
// 8 16B-bank-groups (was 16-lanes-on-4-groups) and keeps stores conflict-free.
#define ASW(t, k) ((((t) * 512 + (k) * 2)) ^ (((t) & 7) << 4))

__device__ __forceinline__ float b2f(ushort_t u) {
    return __uint_as_float(((unsigned)u) << 16);
}
__device__ __forceinline__ ushort_t f2b(float f) {
    unsigned u = __float_as_uint(f);
    unsigned r = (u + 0x7FFFu + ((u >> 16) & 1u)) >> 16;
    return (ushort_t)r;
}
__device__ __forceinline__ float sigm(float x) {
    return __builtin_amdgcn_rcpf(1.f + __expf(-x));
}
__device__ __forceinline__ float tanh_fast(float x) {
    float xx = fminf(fmaxf(x, -15.f), 15.f);
    float t = __expf(2.f * xx);
    return 1.f - 2.f * __builtin_amdgcn_rcpf(t + 1.f);
}
// adaptive int read: int32 (di==0) or int64-low-word (di==1)
__device__ __forceinline__ int iacc(const void* p, long long i, int di) {
    return di ? ((const int*)p)[2 * i] : ((const int*)p)[i];
}

// ---------------- sentinel (f32 out) ------------------------------------------------
__global__ void k_sentinel(float* __restrict__ out, int n, float val) {
    int i = blockIdx.x * 256 + threadIdx.x;
    if (i < n) out[i] = val;
}

// ---------------- tiny int-dtype probe ----------------------------------------------
__global__ void k_det(const int* __restrict__ triples, unsigned* __restrict__ dflag) {
    __shared__ int cnt;
    int tid = threadIdx.x;
    if (tid == 0) cnt = 0;
    __syncthreads();
    int nz = 0;
    for (int i = tid; i < 1500; i += 256)
        if (triples[2 * i + 1] != 0) nz++;
    if (nz) atomicAdd(&cnt, nz);
    __syncthreads();
    if (tid == 0) *dflag = (cnt == 0) ? 2u : 0u;  // bit1: ints are i64
}

// ---------------- prep: Wb[112][256], trelP[500][112], wihT[512][1024] --------------
__global__ void k_prep(const float* __restrict__ Went, const float* __restrict__ wih,
                       const float* __restrict__ relE,
                       ushort_t* __restrict__ Wb, ushort_t* __restrict__ wihT,
                       float* __restrict__ trelP) {
    int i = blockIdx.x * 256 + threadIdx.x;
    int stride = gridDim.x * 256;
    if (i < 112 * 256) {
        int n = i >> 8, k = i & 255;
        float v = 0.f;
        if (n < 100) {
            if (k < 100) v = Went[n * 200 + k];
            else if (k >= 128 && k < 228) v = Went[n * 200 + 100 + (k - 128)];
        }
        Wb[i] = f2b(v);
    }
    for (int j = i; j < 500 * 128; j += stride) {
        int r_ = j >> 7, d = j & 127;
        if (d < 112) trelP[r_ * 112 + d] = (d < 100) ? tanhf(relE[r_ * 100 + d]) : 0.f;
    }
    for (int j = i; j < 512 * 1024; j += stride) {
        int k = j >> 10, n = j & 1023;
        wihT[j] = (k < 500) ? f2b(wih[(long long)n * 500 + k]) : (ushort_t)0;
    }
}

// ---------------- prep2: whhI8 = rint(1024*w_hh) as i8 in MFMA B-fragment order -----
// gate-interleaved n' = u*4 + g  (orig row n = g*256 + u), frag f = ntg*4 + kt;
// lane l, byte j<16: B[n' = ntg*16 + (l&15)][k = kt*64 + (l>>4)*16 + j]
__global__ void k_prep2(const float* __restrict__ whh, uchar_t* __restrict__ whhI8) {
    int j = blockIdx.x * 256 + threadIdx.x;  // < 262144
    int f = j >> 10, r = j & 1023;
    int lane = r >> 4, jj = r & 15;
    int ntg = f >> 2, kt = f & 3;
    int np = ntg * 16 + (lane & 15);
    int k = kt * 64 + ((lane >> 4) << 4) + jj;
    int u = np >> 2, gg = np & 3;
    int qv = __float2int_rn(whh[(gg * 256 + u) * 256 + k] * 1024.f);
    qv = min(max(qv, -127), 127);
    whhI8[j] = (uchar_t)(qv & 0xFF);
}

// ---------------- graph kernel: one block per (b,s), 256 thr, fused transform MFMA --
// 4 waves: 16 gather rows/wave (4-deep in flight); LDS 17.4KB -> 8 blocks/CU = 100%
// static occupancy (waves cap). MFMA/e-phase on waves 0-1; pads zeroed by waves 1-3.
__global__ __launch_bounds__(256, 8) void k_graph(const void* __restrict__ inputs,
                                                  const void* __restrict__ triples,
                                                  const void* __restrict__ id2,
                                                  const float* __restrict__ wordE,
                                                  const float* __restrict__ entE,
                                                  const ushort_t* __restrict__ Wb,
                                                  const float* __restrict__ trelP,
                                                  ushort_t* __restrict__ tfeat,
                                                  const unsigned* __restrict__ dflag) {
    int di = ((*dflag) >> 1) & 1;
    int bs = blockIdx.x;
    int tid = threadIdx.x;
    __shared__ __align__(16) uchar_t As[32 * 512];  // swizzled [t][k] bf16
    __shared__ int hid_sm[32], tl_sm[32], rids[32];
    __shared__ float e_sm[32], alpha[32];
    __shared__ int vflag;
    int wave = tid >> 6, lane = tid & 63;

    if (wave == 0) {
        // triple ids + vflag via ballot (wave-0 only: no init race)
        int idv = -1;
        if (lane < 32) {
            long long base3 = ((long long)bs * 32 + lane) * 3;
            hid_sm[lane] = min(max(iacc(triples, base3, di), 0), NENT - 1);
            tl_sm[lane] = min(max(iacc(triples, base3 + 1, di), 0), NENT - 1);
            rids[lane] = min(max(iacc(triples, base3 + 2, di), 0), NREL - 1);
            idv = iacc(id2, (long long)bs * 32 + lane, di);
        }
        unsigned long long bal = __ballot(idv != -1);
        if (lane == 0) vflag = (bal != 0ULL) ? 1 : 0;
    } else {
        // zero pad columns 100..127 and 228..255 (8B stores, swizzle-safe)
        for (int j = tid - 64; j < 32 * 14; j += 192) {
            int t = j / 14, g = j % 14;
            int c = (g < 7) ? (100 + g * 4) : (228 + (g - 7) * 4);
            *(unsigned long long*)&As[ASW(t, c)] = 0ULL;
        }
    }
    __syncthreads();
    // coalesced entity gather: slot<32 = head row t (cols 0..99), else tail (128..227)
#pragma unroll 4
    for (int slot = wave; slot < 64; slot += 4) {
        int t = slot & 31;
        const float* src = entE + (long long)((slot < 32) ? hid_sm[t] : tl_sm[t]) * 100;
        int cb = (slot < 32) ? 0 : 128;
        if (lane < 50) {
            float2 v = *(const float2*)(src + 2 * lane);
            unsigned pk = ((unsigned)f2b(v.y) << 16) | (unsigned)f2b(v.x);
            *(unsigned*)&As[ASW(t, cb + 2 * lane)] = pk;
        }
    }
    __syncthreads();
    int m16 = lane & 15, q = lane >> 4;
    if (wave < 2) {
        f32x4 acc[7];
#pragma unroll
        for (int nt = 0; nt < 7; nt++) acc[nt] = {0.f, 0.f, 0.f, 0.f};
#pragma unroll
        for (int ks = 0; ks < 8; ++ks) {
            bf16x8 af = *reinterpret_cast<const bf16x8*>(&As[ASW(wave * 16 + m16, ks * 32 + q * 8)]);
#pragma unroll
            for (int nt = 0; nt < 7; ++nt) {
                bf16x8 bf_ = *reinterpret_cast<const bf16x8*>(&Wb[(nt * 16 + m16) * 256 + ks * 32 + q * 8]);
                acc[nt] = __builtin_amdgcn_mfma_f32_16x16x32_bf16(af, bf_, acc[nt], 0, 0, 0);
            }
        }
#pragma unroll
        for (int rr = 0; rr < 4; ++rr) {
            int m = wave * 16 + q * 4 + rr;
            const float* tr = trelP + rids[m] * 112;
            float s = 0.f;
#pragma unroll
            for (int nt = 0; nt < 7; ++nt) s += tanh_fast(acc[nt][rr]) * tr[nt * 16 + m16];
            s += __shfl_xor(s, 1);
            s += __shfl_xor(s, 2);
            s += __shfl_xor(s, 4);
            s += __shfl_xor(s, 8);
            if (m16 == 0) e_sm[m] = s;
        }
    }
    __syncthreads();
    if (tid < 32) {
        float v = e_sm[tid];
        float mx = v;
        for (int off = 16; off >= 1; off >>= 1) mx = fmaxf(mx, __shfl_xor(mx, off));
        float ex = __expf(v - mx);
        float sm = ex;
        for (int off = 16; off >= 1; off >>= 1) sm += __shfl_xor(sm, off);
        alpha[tid] = ex / sm;
    }
    __syncthreads();
    float scale = vflag ? 1.f : 0.f;
    long long row = (long long)bs * KPAD;
    if (tid < 200) {
        int k = tid;
        int kk = (k < 100) ? k : (k + 28);
        float ge = 0.f;
#pragma unroll 8
        for (int tt = 0; tt < 32; ++tt)
            ge += alpha[tt] * b2f(*(const ushort_t*)&As[ASW(tt, kk)]);
        tfeat[row + 300 + k] = f2b(ge * scale);
    }
    int w = min(max(iacc(inputs, bs, di), 0), NVOC - 1);
    const float* wsrc = wordE + (long long)w * 300;
    if (tid < 150) {
        float2 v = *(const float2*)(wsrc + 2 * tid);
        *(unsigned*)&tfeat[row + 2 * tid] = ((unsigned)f2b(v.y) << 16) | (unsigned)f2b(v.x);
    }
    if (tid < 12) tfeat[row + 500 + tid] = 0;
}

// ---------------- GEMM: xw = tfeat @ w_ihT + b_ih + b_hh (bf16, gate-interleaved) ---
// store layout: xwB[i*1024 + (n&255)*4 + (n>>8)]  (unit-major, 4 gates adjacent)
__global__ __launch_bounds__(256) void k_gemm_xw(const ushort_t* __restrict__ A,
                                                 const ushort_t* __restrict__ Bm,
                                                 const float* __restrict__ bih,
                                                 const float* __restrict__ bhh,
                                                 ushort_t* __restrict__ xwB) {
    __shared__ __align__(16) ushort_t As[64 * 32];
    __shared__ __align__(16) ushort_t Bs[64 * 32];
    int tid = threadIdx.x;
    int i0 = blockIdx.x * 64, n0 = blockIdx.y * 64;
    int wave = tid >> 6, lane = tid & 63, m16 = lane & 15, q = lane >> 4;
    f32x4 acc[4];
#pragma unroll
    for (int t = 0; t < 4; t++) acc[t] = {0.f, 0.f, 0.f, 0.f};
    int r = tid >> 2, cq = (tid & 3) * 8;
    int kk = tid >> 3, nn = (tid & 7) * 8;
    for (int kt = 0; kt < 16; ++kt) {
        int k0 = kt * 32;
        {
            const ushort_t* src = A + (i0 + r) * 512 + k0 + cq;
            ushort4 v0 = *(const ushort4*)src;
            ushort4 v1 = *(const ushort4*)(src + 4);
            *(ushort4*)&As[r * 32 + cq] = v0;
            *(ushort4*)&As[r * 32 + cq + 4] = v1;
        }
        {
            const ushort_t* src = Bm + (k0 + kk) * 1024 + n0 + nn;
            ushort4 v0 = *(const ushort4*)(src);
            ushort4 v1 = *(const ushort4*)(src + 4);
            Bs[(nn + 0) * 32 + kk] = v0.x; Bs[(nn + 1) * 32 + kk] = v0.y;
            Bs[(nn + 2) * 32 + kk] = v0.z; Bs[(nn + 3) * 32 + kk] = v0.w;
            Bs[(nn + 4) * 32 + kk] = v1.x; Bs[(nn + 5) * 32 + kk] = v1.y;
            Bs[(nn + 6) * 32 + kk] = v1.z; Bs[(nn + 7) * 32 + kk] = v1.w;
        }
        __syncthreads();
        bf16x8 af = *reinterpret_cast<const bf16x8*>(&As[(wave * 16 + m16) * 32 + q * 8]);
#pragma unroll
        for (int t = 0; t < 4; t++) {
            bf16x8 bf_ = *reinterpret_cast<const bf16x8*>(&Bs[(t * 16 + m16) * 32 + q * 8]);
            acc[t] = __builtin_amdgcn_mfma_f32_16x16x32_bf16(af, bf_, acc[t], 0, 0, 0);
        }
        __syncthreads();
    }
#pragma unroll
    for (int t = 0; t < 4; t++) {
        int n = n0 + t * 16 + m16;
        float bias = bih[n] + bhh[n];
        int ni = ((n & 255) << 2) + (n >> 8);
#pragma unroll
        for (int rr = 0; rr < 4; rr++) {
            int i = i0 + wave * 16 + q * 4 + rr;
            xwB[i * 1024 + ni] = f2b(acc[t][rr] + bias);
        }
    }
}

// ---------------- LSTM scan: 64 blocks x 512 thr, ONE batch row/block, i8 MFMA ------
// w_hh (x1024, i8, gate-interleaved n'=u*4+g) register-resident: 8 waves x 8 ntg x
// 4 kt x 16B. Real data = row 0 only (q=0 lanes, reg 0) -> fanout via 4KB gbuf LDS
// (conflict-free b32 writes, one b128 read per cell). Phase B: 256 lanes x 1 cell.
// 2 lgkm-only barriers/step; hallB global stores never drained in-loop.
__global__ __launch_bounds__(512, 2) void k_lstm(const ushort_t* __restrict__ xwB,
                                                 const uchar_t* __restrict__ whhI8,
                                                 const void* __restrict__ lengths,
                                                 ushort_t* __restrict__ hallB,
                                                 const unsigned* __restrict__ dflag) {
    const int LDH = 272;  // hsm row stride bytes (non-pow2: staggers A-frag read banks)
    int di = ((*dflag) >> 1) & 1;
    int b = blockIdx.x;  // one batch row per block
    int tid = threadIdx.x;
    int wave = tid >> 6, lane = tid & 63;
    int c16 = lane & 15, q = lane >> 4;
    __shared__ __align__(16) uchar_t hsm[16 * 272];  // h*127 as i8; rows 1..15 stay 0
    __shared__ __align__(16) float gbuf[1024];       // gates_hh*(127*1024) as f32, [n']
    for (int j = tid; j < 16 * 272; j += 512) hsm[j] = 0;
    // register-resident weight fragments (once): wreg[i][kt] for ntg = wave*8+i
    i32x4 wreg[8][4];
    {
        const uchar_t* wp = whhI8 + (((long long)(wave * 8) * 4) * 64 + lane) * 16;
#pragma unroll
        for (int i = 0; i < 8; ++i)
#pragma unroll
            for (int kt = 0; kt < 4; ++kt)
                wreg[i][kt] = *(const i32x4*)(wp + (((i << 2) + kt) << 10));
    }
    int len = iacc(lengths, b, di);
    int u = tid;  // cell unit for tid<256
    float cc = 0.f;
    const float S = 1.f / (127.f * 1024.f);
    long long xbase = ((long long)(b * 128) << 10) + ((long long)u << 2);
    ushort4 xv = {0, 0, 0, 0}, xn;
    if (tid < 256) xv = *(const ushort4*)(xwB + xbase);
    __syncthreads();
    for (int s = 0; s < 128; ++s) {
        // phase A operands: h row-slab (A-frag: row=c16, k = kt*64 + q*16 + j)
        const uchar_t* hb = &hsm[c16 * LDH];
        i32x4 afr[4];
#pragma unroll
        for (int kt = 0; kt < 4; ++kt)
            afr[kt] = *(const i32x4*)(hb + kt * 64 + q * 16);
        // prefetch next step's xw early (before any stores this step)
        int sn = (s < 127) ? s + 1 : 127;
        if (tid < 256) xn = *(const ushort4*)(xwB + xbase + ((long long)sn << 10));
#pragma unroll
        for (int i = 0; i < 8; ++i) {
            i32x4 a = {0, 0, 0, 0};
#pragma unroll
            for (int kt = 0; kt < 4; ++kt)
                a = __builtin_amdgcn_mfma_i32_16x16x64_i8(afr[kt], wreg[i][kt], a, 0, 0, 0);
            if (q == 0) gbuf[(wave * 8 + i) * 16 + c16] = (float)a[0];  // row 0 only
        }
        asm volatile("s_waitcnt lgkmcnt(0)\n\ts_barrier" ::: "memory");
        if (tid < 256) {
            f32x4 gv = *(const f32x4*)&gbuf[u * 4];  // gates i,f,g,o of unit u
            float iv = b2f(xv.x) + gv[0] * S;
            float fv = b2f(xv.y) + gv[1] * S;
            float gg = b2f(xv.z) + gv[2] * S;
            float ov = b2f(xv.w) + gv[3] * S;
            float c = sigm(fv) * cc + sigm(iv) * tanh_fast(gg);
            float h = sigm(ov) * tanh_fast(c);
            cc = c;
            hsm[u] = (uchar_t)(__float2int_rn(h * 127.f) & 0xFF);
            hallB[((long long)(b * 128 + s) << 8) + u] = (s < len) ? f2b(h) : (ushort_t)0;
            xv = xn;
        }
        asm volatile("s_waitcnt lgkmcnt(0)\n\ts_barrier" ::: "memory");
    }
}

// ---------------- attention + classifier head (f32 out) -----------------------------
__global__ __launch_bounds__(256) void k_att(const ushort_t* __restrict__ hallB,
                                             const float* __restrict__ Watt,
                                             const float* __restrict__ batt,
                                             const float* __restrict__ Wout,
                                             const float* __restrict__ bout,
                                             float* __restrict__ out) {
    int b = blockIdx.x, tid = threadIdx.x;
    __shared__ float waf[256], lg[128], msk[128], ps[128], enc[256], o3[3], red[1];
    waf[tid] = Watt[tid];
    __syncthreads();
    int s = tid >> 1, half = tid & 1;
    const ushort_t* hb = hallB + (b * 128 + s) * 256 + half * 128;
    float part = 0.f;
    for (int j = 0; j < 128; ++j) part += b2f(hb[j]) * waf[half * 128 + j];
    part += __shfl_xor(part, 1);
    if (half == 0) lg[s] = part + batt[0];
    __syncthreads();
    if (tid < 128) {
        float lv = lg[tid];
        float m = (lv != 0.f) ? 1.f : 0.f;
        msk[tid] = m;
        lg[tid] = lv * m;
    }
    __syncthreads();
    if (tid == 0) {
        float mx = -1e30f;
        for (int i = 0; i < 128; ++i) mx = fmaxf(mx, lg[i]);
        red[0] = mx;
    }
    __syncthreads();
    if (tid < 128) ps[tid] = __expf(lg[tid] - red[0]);
    __syncthreads();
    if (tid == 0) {
        float sm = 0.f;
        for (int i = 0; i < 128; ++i) sm += ps[i];
        red[0] = sm;
    }
    __syncthreads();
    if (tid < 128) ps[tid] = ps[tid] / red[0] * msk[tid];
    __syncthreads();
    if (tid == 0) {
        float sm = 0.f;
        for (int i = 0; i < 128; ++i) sm += ps[i];
        red[0] = sm + 1e-13f;
    }
    __syncthreads();
    if (tid < 128) {
        float p = ps[tid] / red[0];
        ps[tid] = p;
        out[192 + b * 128 + tid] = p;
    }
    __syncthreads();
    {
        float ej = 0.f;
        for (int ss = 0; ss < 128; ++ss) ej += ps[ss] * b2f(hallB[(b * 128 + ss) * 256 + tid]);
        enc[tid] = ej;
    }
    __syncthreads();
    if (tid < 3) {
        float a = 0.f;
        for (int j = 0; j < 256; ++j) a += enc[j] * Wout[tid * 256 + j];
        o3[tid] = a + bout[tid];
    }
    __syncthreads();
    if (tid == 0) {
        float m = fmaxf(o3[0], fmaxf(o3[1], o3[2]));
        float l = logf(__expf(o3[0] - m) + __expf(o3[1] - m) + __expf(o3[2] - m)) + m;
        out[b * 3 + 0] = o3[0] - l;
        out[b * 3 + 1] = o3[1] - l;
        out[b * 3 + 2] = o3[2] - l;
    }
}

extern "C" void kernel_launch(void* const* d_in, const int* in_sizes, int n_in,
                              void* d_out, int out_size, void* d_ws, size_t ws_size,
                              hipStream_t stream) {
    float* out = (float*)d_out;
    static const long long EXP[16] = {8192, 786432, 64, 262144, 15000000, 20000000,
                                      50000, 20000, 512000, 262144, 1024, 1024,
                                      256, 1, 768, 3};
    int ob = (out_size + 255) / 256;
    if (n_in != 16 || out_size != 8384) {
        hipLaunchKernelGGL(k_sentinel, dim3(ob), dim3(256), 0, stream, out, out_size, -8192.f);
        return;
    }
    for (int i = 0; i < 16; ++i) {
        if ((long long)in_sizes[i] != EXP[i]) {
            hipLaunchKernelGGL(k_sentinel, dim3(ob), dim3(256), 0, stream, out, out_size,
                               -(4096.f + 32.f * i));
            return;
        }
    }

    const void* inputs = d_in[0];
    const void* triples = d_in[1];
    const void* lengths = d_in[2];
    const void* id2 = d_in[3];
    const float* wordE = (const float*)d_in[4];
    const float* entE = (const float*)d_in[5];
    const float* relE = (const float*)d_in[6];
    const float* Went = (const float*)d_in[7];
    const float* wih = (const float*)d_in[8];
    const float* whh = (const float*)d_in[9];
    const float* bih = (const float*)d_in[10];
    const float* bhh = (const float*)d_in[11];
    const float* Watt = (const float*)d_in[12];
    const float* batt = (const float*)d_in[13];
    const float* Wout = (const float*)d_in[14];
    const float* bout = (const float*)d_in[15];
    char* ws = (char*)d_ws;

    // workspace layout — total 26,496,000 B (< proven 27,028,224)
    constexpr size_t OFF_XW = 0;            // ushort 8192*1024*2 = 16,777,216
    constexpr size_t OFF_TFEAT = 16777216;  // ushort 8192*512*2 = 8,388,608 (hallB overlays)
    constexpr size_t OFF_WIHT = 25165824;   // ushort 512*1024*2 = 1,048,576 (whhI8 overlays after gemm)
    constexpr size_t OFF_WB = 26214400;     // ushort 112*256*2 = 57,344
    constexpr size_t OFF_FLAGS = 26271744;  // u32 dflag
    constexpr size_t OFF_TRELP = 26272000;  // float 500*112*4 = 224,000 -> end 26,496,000
    constexpr size_t WS_NEEDED = 26496000;

    if (ws_size < WS_NEEDED) {
        hipLaunchKernelGGL(k_sentinel, dim3(ob), dim3(256), 0, stream, out, out_size,
                           -(float)(ws_size >> 20));
        return;
    }

    ushort_t* xwB = (ushort_t*)(ws + OFF_XW);
    ushort_t* tfeat = (ushort_t*)(ws + OFF_TFEAT);
    ushort_t* hallB = (ushort_t*)(ws + OFF_TFEAT);  // overlays tfeat after k_gemm_xw
    ushort_t* wihT = (ushort_t*)(ws + OFF_WIHT);
    uchar_t* whhI8 = (uchar_t*)(ws + OFF_WIHT);     // overlays wihT after k_gemm_xw
    ushort_t* Wb = (ushort_t*)(ws + OFF_WB);
    unsigned* dflag = (unsigned*)(ws + OFF_FLAGS);
    float* trelP = (float*)(ws + OFF_TRELP);

    hipLaunchKernelGGL(k_det, dim3(1), dim3(256), 0, stream, (const int*)triples, dflag);
    hipLaunchKernelGGL(k_prep, dim3(2048), dim3(256), 0, stream,
                       Went, wih, relE, Wb, wihT, trelP);
    hipLaunchKernelGGL(k_graph, dim3(8192), dim3(256), 0, stream,
                       inputs, triples, id2, wordE, entE, Wb, trelP, tfeat, dflag);
    hipLaunchKernelGGL(k_gemm_xw, dim3(128, 16), dim3(256), 0, stream,
                       tfeat, wihT, bih, bhh, xwB);
    hipLaunchKernelGGL(k_prep2, dim3(1024), dim3(256), 0, stream, whh, whhI8);
    hipLaunchKernelGGL(k_lstm, dim3(64), dim3(512), 0, stream, xwB, whhI8, lengths, hallB, dflag);
    hipLaunchKernelGGL(k_att, dim3(64), dim3(256), 0, stream, hallB, Watt, batt, Wout, bout, out);
}

// Round 7
// 485.792 us; speedup vs baseline: 1.5361x; 1.0168x over previous
//
#include <hip/hip_runtime.h>

// RNNSequenceClassifier on MI355X. Inputs/outputs are FLOAT32 (proven R4/R5).
// prep (incl. entE -> fp8 e4m3 x64 table, 100B rows = 2.5 lines vs 7) -> graph/t_feat
// (fp8 gather + swizzled LDS + fused transform MFMA; emits graphE[200] + tokIds only)
// -> xw GEMM (A = wordE-direct f32 + graphE bf16; MFMA, gate-interleaved bf16 out)
// -> prep2 (whh -> i8 MFMA B-frags) -> i8-MFMA LSTM scan (64 blocks x 1 row, weights
// register-resident) -> attention/head.

typedef unsigned short ushort_t;
typedef unsigned char uchar_t;
typedef __bf16 bf16x8 __attribute__((ext_vector_type(8)));
typedef float f32x4 __attribute__((ext_vector_type(4)));
typedef int i32x4 __attribute__((ext_vector_type(4)));

#define NENT 200000
#define NVOC 50000
#define NREL 500
// swizzled byte offset into As[32][256] bf16: spreads b128 A-frag reads across all
// 8 16B-bank-groups and keeps stores conflict-free.
#define ASW(t, k) ((((t) * 512 + (k) * 2)) ^ (((t) & 7) << 4))

__device__ __forceinline__ float b2f(ushort_t u) {
    return __uint_as_float(((unsigned)u) << 16);
}
__device__ __forceinline__ ushort_t f2b(float f) {
    unsigned u = __float_as_uint(f);
    unsigned r = (u + 0x7FFFu + ((u >> 16) & 1u)) >> 16;
    return (ushort_t)r;
}
__device__ __forceinline__ float sigm(float x) {
    return __builtin_amdgcn_rcpf(1.f + __expf(-x));
}
__device__ __forceinline__ float tanh_fast(float x) {
    float xx = fminf(fmaxf(x, -15.f), 15.f);
    float t = __expf(2.f * xx);
    return 1.f - 2.f * __builtin_amdgcn_rcpf(t + 1.f);
}
// float -> OCP e4m3fn (RNE), hand-rolled (proven in R0 kernel)
__device__ __forceinline__ uchar_t f2fp8(float x) {
    unsigned s = (__float_as_uint(x) >> 24) & 0x80u;
    float ax = fabsf(x);
    if (ax >= 448.f) return (uchar_t)(s | 0x7E);
    if (ax < 0.015625f) {  // subnormal: q = RNE(ax * 2^9); q==8 rolls into E=1,m=0
        float t = ax * 512.f + 12582912.f;  // 1.5*2^23 magic RNE
        unsigned q = __float_as_uint(t) & 0xFFu;
        return (uchar_t)(s | q);
    }
    unsigned au = __float_as_uint(ax);
    unsigned lsb = (au >> 20) & 1u;
    au += 0x0007FFFFu + lsb;  // RNE at mantissa bit 20 (keeps 3 bits)
    int E = ((int)(au >> 23) & 0xFF) - 127 + 7;
    unsigned f3 = (au >> 20) & 7u;
    if (E >= 16) return (uchar_t)(s | 0x7E);
    return (uchar_t)(s | ((unsigned)E << 3) | f3);
}
// decode e4m3fn byte and divide by 64 (table scale), matched to f2fp8
__device__ __forceinline__ float fp8d64(unsigned b) {
    unsigned E = (b >> 3) & 15u, m = b & 7u;
    float nrm = __uint_as_float(((b & 0x80u) << 24) | ((E + 114u) << 23) | (m << 20));
    float sub = (float)(int)m * 3.0517578125e-05f;  // m * 2^-9 / 64
    if (b & 0x80u) sub = -sub;
    return E ? nrm : sub;
}
// adaptive int read: int32 (di==0) or int64-low-word (di==1)
__device__ __forceinline__ int iacc(const void* p, long long i, int di) {
    return di ? ((const int*)p)[2 * i] : ((const int*)p)[i];
}

// ---------------- sentinel (f32 out) ------------------------------------------------
__global__ void k_sentinel(float* __restrict__ out, int n, float val) {
    int i = blockIdx.x * 256 + threadIdx.x;
    if (i < n) out[i] = val;
}

// ---------------- tiny int-dtype probe ----------------------------------------------
__global__ void k_det(const int* __restrict__ triples, unsigned* __restrict__ dflag) {
    __shared__ int cnt;
    int tid = threadIdx.x;
    if (tid == 0) cnt = 0;
    __syncthreads();
    int nz = 0;
    for (int i = tid; i < 1500; i += 256)
        if (triples[2 * i + 1] != 0) nz++;
    if (nz) atomicAdd(&cnt, nz);
    __syncthreads();
    if (tid == 0) *dflag = (cnt == 0) ? 2u : 0u;  // bit1: ints are i64
}

// ---------------- prep: Wb[112][256], trelP[500][112], wihT[512][1024], entE8 -------
__global__ void k_prep(const float* __restrict__ Went, const float* __restrict__ wih,
                       const float* __restrict__ relE, const float* __restrict__ entE,
                       ushort_t* __restrict__ Wb, ushort_t* __restrict__ wihT,
                       float* __restrict__ trelP, uchar_t* __restrict__ entE8) {
    int i = blockIdx.x * 256 + threadIdx.x;
    int stride = gridDim.x * 256;
    if (i < 112 * 256) {
        int n = i >> 8, k = i & 255;
        float v = 0.f;
        if (n < 100) {
            if (k < 100) v = Went[n * 200 + k];
            else if (k >= 128 && k < 228) v = Went[n * 200 + 100 + (k - 128)];
        }
        Wb[i] = f2b(v);
    }
    for (int j = i; j < 500 * 128; j += stride) {
        int r_ = j >> 7, d = j & 127;
        if (d < 112) trelP[r_ * 112 + d] = (d < 100) ? tanhf(relE[r_ * 100 + d]) : 0.f;
    }
    for (int j = i; j < 512 * 1024; j += stride) {
        int k = j >> 10, n = j & 1023;
        wihT[j] = (k < 500) ? f2b(wih[(long long)n * 500 + k]) : (ushort_t)0;
    }
    // fp8 entity table (x64): 20M elements, coalesced stream
    for (int j = i; j < 20000000; j += stride) entE8[j] = f2fp8(entE[j] * 64.f);
}

// ---------------- prep2: whhI8 = rint(1024*w_hh) as i8 in MFMA B-fragment order -----
// gate-interleaved n' = u*4 + g  (orig row n = g*256 + u), frag f = ntg*4 + kt;
// lane l, byte j<16: B[n' = ntg*16 + (l&15)][k = kt*64 + (l>>4)*16 + j]
__global__ void k_prep2(const float* __restrict__ whh, uchar_t* __restrict__ whhI8) {
    int j = blockIdx.x * 256 + threadIdx.x;  // < 262144
    int f = j >> 10, r = j & 1023;
    int lane = r >> 4, jj = r & 15;
    int ntg = f >> 2, kt = f & 3;
    int np = ntg * 16 + (lane & 15);
    int k = kt * 64 + ((lane >> 4) << 4) + jj;
    int u = np >> 2, gg = np & 3;
    int qv = __float2int_rn(whh[(gg * 256 + u) * 256 + k] * 1024.f);
    qv = min(max(qv, -127), 127);
    whhI8[j] = (uchar_t)(qv & 0xFF);
}

// ---------------- graph kernel: one block per (b,s), 256 thr, fused transform MFMA --
// fp8 entity gather: 2 rows per wave-iter (25 lanes x dword each), decode+pack to
// swizzled bf16 As. Emits graphE[bs][200] bf16 + tokIds[bs] only (word part read
// directly by k_gemm_xw).
__global__ __launch_bounds__(256, 8) void k_graph(const void* __restrict__ inputs,
                                                  const void* __restrict__ triples,
                                                  const void* __restrict__ id2,
                                                  const uchar_t* __restrict__ entE8,
                                                  const ushort_t* __restrict__ Wb,
                                                  const float* __restrict__ trelP,
                                                  ushort_t* __restrict__ graphE,
                                                  int* __restrict__ tokIds,
                                                  const unsigned* __restrict__ dflag) {
    int di = ((*dflag) >> 1) & 1;
    int bs = blockIdx.x;
    int tid = threadIdx.x;
    __shared__ __align__(16) uchar_t As[32 * 512];  // swizzled [t][k] bf16
    __shared__ int hid_sm[32], tl_sm[32], rids[32];
    __shared__ float e_sm[32], alpha[32];
    __shared__ int vflag;
    int wave = tid >> 6, lane = tid & 63;

    if (wave == 0) {
        // triple ids + vflag via ballot (wave-0 only: no init race)
        int idv = -1;
        if (lane < 32) {
            long long base3 = ((long long)bs * 32 + lane) * 3;
            hid_sm[lane] = min(max(iacc(triples, base3, di), 0), NENT - 1);
            tl_sm[lane] = min(max(iacc(triples, base3 + 1, di), 0), NENT - 1);
            rids[lane] = min(max(iacc(triples, base3 + 2, di), 0), NREL - 1);
            idv = iacc(id2, (long long)bs * 32 + lane, di);
        }
        unsigned long long bal = __ballot(idv != -1);
        if (lane == 0) vflag = (bal != 0ULL) ? 1 : 0;
    } else {
        // zero pad columns 100..127 and 228..255 (8B stores, swizzle-safe)
        for (int j = tid - 64; j < 32 * 14; j += 192) {
            int t = j / 14, g = j % 14;
            int c = (g < 7) ? (100 + g * 4) : (228 + (g - 7) * 4);
            *(unsigned long long*)&As[ASW(t, c)] = 0ULL;
        }
    }
    __syncthreads();
    // fp8 entity gather: slot<32 = head row t (cols 0..99), else tail (128..227).
    // 2 slots per wave-iteration: half-wave sub (25 of 32 lanes) loads one dword each.
    int sub = lane >> 5, li = lane & 31;
#pragma unroll 4
    for (int pr = wave * 2; pr < 64; pr += 8) {
        int slot = pr + sub;
        int t = slot & 31;
        const uchar_t* src = entE8 + (long long)((slot < 32) ? hid_sm[t] : tl_sm[t]) * 100;
        int cb = (slot < 32) ? 0 : 128;
        if (li < 25) {
            unsigned w4 = *(const unsigned*)(src + 4 * li);
            float f0 = fp8d64(w4 & 255u), f1 = fp8d64((w4 >> 8) & 255u);
            float f2_ = fp8d64((w4 >> 16) & 255u), f3 = fp8d64(w4 >> 24);
            unsigned lo = ((unsigned)f2b(f1) << 16) | (unsigned)f2b(f0);
            unsigned hi = ((unsigned)f2b(f3) << 16) | (unsigned)f2b(f2_);
            unsigned long long pk = ((unsigned long long)hi << 32) | lo;
            *(unsigned long long*)&As[ASW(t, cb + 4 * li)] = pk;
        }
    }
    __syncthreads();
    int m16 = lane & 15, q = lane >> 4;
    if (wave < 2) {
        f32x4 acc[7];
#pragma unroll
        for (int nt = 0; nt < 7; nt++) acc[nt] = {0.f, 0.f, 0.f, 0.f};
#pragma unroll
        for (int ks = 0; ks < 8; ++ks) {
            bf16x8 af = *reinterpret_cast<const bf16x8*>(&As[ASW(wave * 16 + m16, ks * 32 + q * 8)]);
#pragma unroll
            for (int nt = 0; nt < 7; ++nt) {
                bf16x8 bf_ = *reinterpret_cast<const bf16x8*>(&Wb[(nt * 16 + m16) * 256 + ks * 32 + q * 8]);
                acc[nt] = __builtin_amdgcn_mfma_f32_16x16x32_bf16(af, bf_, acc[nt], 0, 0, 0);
            }
        }
#pragma unroll
        for (int rr = 0; rr < 4; ++rr) {
            int m = wave * 16 + q * 4 + rr;
            const float* tr = trelP + rids[m] * 112;
            float s = 0.f;
#pragma unroll
            for (int nt = 0; nt < 7; ++nt) s += tanh_fast(acc[nt][rr]) * tr[nt * 16 + m16];
            s += __shfl_xor(s, 1);
            s += __shfl_xor(s, 2);
            s += __shfl_xor(s, 4);
            s += __shfl_xor(s, 8);
            if (m16 == 0) e_sm[m] = s;
        }
    }
    __syncthreads();
    if (tid < 32) {
        float v = e_sm[tid];
        float mx = v;
        for (int off = 16; off >= 1; off >>= 1) mx = fmaxf(mx, __shfl_xor(mx, off));
        float ex = __expf(v - mx);
        float sm = ex;
        for (int off = 16; off >= 1; off >>= 1) sm += __shfl_xor(sm, off);
        alpha[tid] = ex / sm;
    }
    __syncthreads();
    float scale = vflag ? 1.f : 0.f;
    if (tid < 200) {
        int k = tid;
        int kk = (k < 100) ? k : (k + 28);
        float ge = 0.f;
#pragma unroll 8
        for (int tt = 0; tt < 32; ++tt)
            ge += alpha[tt] * b2f(*(const ushort_t*)&As[ASW(tt, kk)]);
        graphE[(long long)bs * 200 + k] = f2b(ge * scale);
    }
    if (tid == 0) tokIds[bs] = min(max(iacc(inputs, bs, di), 0), NVOC - 1);
}

// ---------------- GEMM: xw = [wordE | graphE] @ w_ihT + b_ih + b_hh ------------------
// A assembled on the fly: k<300 from wordE (f32, vectorized), 300<=k<500 from graphE
// (bf16), k>=500 zero. store layout: xwB[i*1024 + (n&255)*4 + (n>>8)].
__global__ __launch_bounds__(256) void k_gemm_xw(const ushort_t* __restrict__ graphE,
                                                 const int* __restrict__ tokIds,
                                                 const float* __restrict__ wordE,
                                                 const ushort_t* __restrict__ Bm,
                                                 const float* __restrict__ bih,
                                                 const float* __restrict__ bhh,
                                                 ushort_t* __restrict__ xwB) {
    __shared__ __align__(16) ushort_t As[64 * 32];
    __shared__ __align__(16) ushort_t Bs[64 * 32];
    int tid = threadIdx.x;
    int i0 = blockIdx.x * 64, n0 = blockIdx.y * 64;
    int wave = tid >> 6, lane = tid & 63, m16 = lane & 15, q = lane >> 4;
    f32x4 acc[4];
#pragma unroll
    for (int t = 0; t < 4; t++) acc[t] = {0.f, 0.f, 0.f, 0.f};
    int r = tid >> 2, cq = (tid & 3) * 8;
    int kk = tid >> 3, nn = (tid & 7) * 8;
    int iA = i0 + r;
    const float* wrow = wordE + (long long)tokIds[iA] * 300;
    const ushort_t* grow = graphE + (long long)iA * 200;
    for (int kt = 0; kt < 16; ++kt) {
        int k0 = kt * 32;
        {
            int kb = k0 + cq;
            ushort_t av[8];
            if (kb + 8 <= 300) {  // pure word tile: vectorized f32
                f32x4 w0 = *(const f32x4*)(wrow + kb);
                f32x4 w1 = *(const f32x4*)(wrow + kb + 4);
#pragma unroll
                for (int j = 0; j < 4; ++j) av[j] = f2b(w0[j]);
#pragma unroll
                for (int j = 0; j < 4; ++j) av[4 + j] = f2b(w1[j]);
            } else if (kb >= 304 && kb + 8 <= 500) {  // pure graph tile: bf16 copy
                ushort4 g0 = *(const ushort4*)(grow + kb - 300);
                ushort4 g1 = *(const ushort4*)(grow + kb - 296);
                av[0] = g0.x; av[1] = g0.y; av[2] = g0.z; av[3] = g0.w;
                av[4] = g1.x; av[5] = g1.y; av[6] = g1.z; av[7] = g1.w;
            } else {  // boundary tiles (kb = 296, 496) and zero tail
#pragma unroll
                for (int j = 0; j < 8; ++j) {
                    int k = kb + j;
                    ushort_t v = 0;
                    if (k < 300) v = f2b(wrow[k]);
                    else if (k < 500) v = grow[k - 300];
                    av[j] = v;
                }
            }
            *(ushort4*)&As[r * 32 + cq] = *(ushort4*)&av[0];
            *(ushort4*)&As[r * 32 + cq + 4] = *(ushort4*)&av[4];
        }
        {
            const ushort_t* src = Bm + (k0 + kk) * 1024 + n0 + nn;
            ushort4 v0 = *(const ushort4*)(src);
            ushort4 v1 = *(const ushort4*)(src + 4);
            Bs[(nn + 0) * 32 + kk] = v0.x; Bs[(nn + 1) * 32 + kk] = v0.y;
            Bs[(nn + 2) * 32 + kk] = v0.z; Bs[(nn + 3) * 32 + kk] = v0.w;
            Bs[(nn + 4) * 32 + kk] = v1.x; Bs[(nn + 5) * 32 + kk] = v1.y;
            Bs[(nn + 6) * 32 + kk] = v1.z; Bs[(nn + 7) * 32 + kk] = v1.w;
        }
        __syncthreads();
        bf16x8 af = *reinterpret_cast<const bf16x8*>(&As[(wave * 16 + m16) * 32 + q * 8]);
#pragma unroll
        for (int t = 0; t < 4; t++) {
            bf16x8 bf_ = *reinterpret_cast<const bf16x8*>(&Bs[(t * 16 + m16) * 32 + q * 8]);
            acc[t] = __builtin_amdgcn_mfma_f32_16x16x32_bf16(af, bf_, acc[t], 0, 0, 0);
        }
        __syncthreads();
    }
#pragma unroll
    for (int t = 0; t < 4; t++) {
        int n = n0 + t * 16 + m16;
        float bias = bih[n] + bhh[n];
        int ni = ((n & 255) << 2) + (n >> 8);
#pragma unroll
        for (int rr = 0; rr < 4; rr++) {
            int i = i0 + wave * 16 + q * 4 + rr;
            xwB[i * 1024 + ni] = f2b(acc[t][rr] + bias);
        }
    }
}

// ---------------- LSTM scan: 64 blocks x 512 thr, ONE batch row/block, i8 MFMA ------
// w_hh (x1024, i8, gate-interleaved n'=u*4+g) register-resident: 8 waves x 8 ntg x
// 4 kt x 16B. Real data = row 0 only (q=0 lanes, reg 0) -> fanout via 4KB gbuf LDS
// (conflict-free b32 writes, one b128 read per cell). Phase B: 256 lanes x 1 cell.
// 2 lgkm-only barriers/step; hallB global stores never drained in-loop.
__global__ __launch_bounds__(512, 2) void k_lstm(const ushort_t* __restrict__ xwB,
                                                 const uchar_t* __restrict__ whhI8,
                                                 const void* __restrict__ lengths,
                                                 ushort_t* __restrict__ hallB,
                                                 const unsigned* __restrict__ dflag) {
    const int LDH = 272;  // hsm row stride bytes (non-pow2: staggers A-frag read banks)
    int di = ((*dflag) >> 1) & 1;
    int b = blockIdx.x;  // one batch row per block
    int tid = threadIdx.x;
    int wave = tid >> 6, lane = tid & 63;
    int c16 = lane & 15, q = lane >> 4;
    __shared__ __align__(16) uchar_t hsm[16 * 272];  // h*127 as i8; rows 1..15 stay 0
    __shared__ __align__(16) float gbuf[1024];       // gates_hh*(127*1024) as f32, [n']
    for (int j = tid; j < 16 * 272; j += 512) hsm[j] = 0;
    // register-resident weight fragments (once): wreg[i][kt] for ntg = wave*8+i
    i32x4 wreg[8][4];
    {
        const uchar_t* wp = whhI8 + (((long long)(wave * 8) * 4) * 64 + lane) * 16;
#pragma unroll
        for (int i = 0; i < 8; ++i)
#pragma unroll
            for (int kt = 0; kt < 4; ++kt)
                wreg[i][kt] = *(const i32x4*)(wp + (((i << 2) + kt) << 10));
    }
    int len = iacc(lengths, b, di);
    int u = tid;  // cell unit for tid<256
    float cc = 0.f;
    const float S = 1.f / (127.f * 1024.f);
    long long xbase = ((long long)(b * 128) << 10) + ((long long)u << 2);
    ushort4 xv = {0, 0, 0, 0}, xn;
    if (tid < 256) xv = *(const ushort4*)(xwB + xbase);
    __syncthreads();
    for (int s = 0; s < 128; ++s) {
        // phase A operands: h row-slab (A-frag: row=c16, k = kt*64 + q*16 + j)
        const uchar_t* hb = &hsm[c16 * LDH];
        i32x4 afr[4];
#pragma unroll
        for (int kt = 0; kt < 4; ++kt)
            afr[kt] = *(const i32x4*)(hb + kt * 64 + q * 16);
        // prefetch next step's xw early (before any stores this step)
        int sn = (s < 127) ? s + 1 : 127;
        if (tid < 256) xn = *(const ushort4*)(xwB + xbase + ((long long)sn << 10));
#pragma unroll
        for (int i = 0; i < 8; ++i) {
            i32x4 a = {0, 0, 0, 0};
#pragma unroll
            for (int kt = 0; kt < 4; ++kt)
                a = __builtin_amdgcn_mfma_i32_16x16x64_i8(afr[kt], wreg[i][kt], a, 0, 0, 0);
            if (q == 0) gbuf[(wave * 8 + i) * 16 + c16] = (float)a[0];  // row 0 only
        }
        asm volatile("s_waitcnt lgkmcnt(0)\n\ts_barrier" ::: "memory");
        if (tid < 256) {
            f32x4 gv = *(const f32x4*)&gbuf[u * 4];  // gates i,f,g,o of unit u
            float iv = b2f(xv.x) + gv[0] * S;
            float fv = b2f(xv.y) + gv[1] * S;
            float gg = b2f(xv.z) + gv[2] * S;
            float ov = b2f(xv.w) + gv[3] * S;
            float c = sigm(fv) * cc + sigm(iv) * tanh_fast(gg);
            float h = sigm(ov) * tanh_fast(c);
            cc = c;
            hsm[u] = (uchar_t)(__float2int_rn(h * 127.f) & 0xFF);
            hallB[((long long)(b * 128 + s) << 8) + u] = (s < len) ? f2b(h) : (ushort_t)0;
            xv = xn;
        }
        asm volatile("s_waitcnt lgkmcnt(0)\n\ts_barrier" ::: "memory");
    }
}

// ---------------- attention + classifier head (f32 out) -----------------------------
__global__ __launch_bounds__(256) void k_att(const ushort_t* __restrict__ hallB,
                                             const float* __restrict__ Watt,
                                             const float* __restrict__ batt,
                                             const float* __restrict__ Wout,
                                             const float* __restrict__ bout,
                                             float* __restrict__ out) {
    int b = blockIdx.x, tid = threadIdx.x;
    __shared__ float waf[256], lg[128], msk[128], ps[128], enc[256], o3[3], red[1];
    waf[tid] = Watt[tid];
    __syncthreads();
    int s = tid >> 1, half = tid & 1;
    const ushort_t* hb = hallB + (b * 128 + s) * 256 + half * 128;
    float part = 0.f;
    for (int j = 0; j < 128; ++j) part += b2f(hb[j]) * waf[half * 128 + j];
    part += __shfl_xor(part, 1);
    if (half == 0) lg[s] = part + batt[0];
    __syncthreads();
    if (tid < 128) {
        float lv = lg[tid];
        float m = (lv != 0.f) ? 1.f : 0.f;
        msk[tid] = m;
        lg[tid] = lv * m;
    }
    __syncthreads();
    if (tid == 0) {
        float mx = -1e30f;
        for (int i = 0; i < 128; ++i) mx = fmaxf(mx, lg[i]);
        red[0] = mx;
    }
    __syncthreads();
    if (tid < 128) ps[tid] = __expf(lg[tid] - red[0]);
    __syncthreads();
    if (tid == 0) {
        float sm = 0.f;
        for (int i = 0; i < 128; ++i) sm += ps[i];
        red[0] = sm;
    }
    __syncthreads();
    if (tid < 128) ps[tid] = ps[tid] / red[0] * msk[tid];
    __syncthreads();
    if (tid == 0) {
        float sm = 0.f;
        for (int i = 0; i < 128; ++i) sm += ps[i];
        red[0] = sm + 1e-13f;
    }
    __syncthreads();
    if (tid < 128) {
        float p = ps[tid] / red[0];
        ps[tid] = p;
        out[192 + b * 128 + tid] = p;
    }
    __syncthreads();
    {
        float ej = 0.f;
        for (int ss = 0; ss < 128; ++ss) ej += ps[ss] * b2f(hallB[(b * 128 + ss) * 256 + tid]);
        enc[tid] = ej;
    }
    __syncthreads();
    if (tid < 3) {
        float a = 0.f;
        for (int j = 0; j < 256; ++j) a += enc[j] * Wout[tid * 256 + j];
        o3[tid] = a + bout[tid];
    }
    __syncthreads();
    if (tid == 0) {
        float m = fmaxf(o3[0], fmaxf(o3[1], o3[2]));
        float l = logf(__expf(o3[0] - m) + __expf(o3[1] - m) + __expf(o3[2] - m)) + m;
        out[b * 3 + 0] = o3[0] - l;
        out[b * 3 + 1] = o3[1] - l;
        out[b * 3 + 2] = o3[2] - l;
    }
}

extern "C" void kernel_launch(void* const* d_in, const int* in_sizes, int n_in,
                              void* d_out, int out_size, void* d_ws, size_t ws_size,
                              hipStream_t stream) {
    float* out = (float*)d_out;
    static const long long EXP[16] = {8192, 786432, 64, 262144, 15000000, 20000000,
                                      50000, 20000, 512000, 262144, 1024, 1024,
                                      256, 1, 768, 3};
    int ob = (out_size + 255) / 256;
    if (n_in != 16 || out_size != 8384) {
        hipLaunchKernelGGL(k_sentinel, dim3(ob), dim3(256), 0, stream, out, out_size, -8192.f);
        return;
    }
    for (int i = 0; i < 16; ++i) {
        if ((long long)in_sizes[i] != EXP[i]) {
            hipLaunchKernelGGL(k_sentinel, dim3(ob), dim3(256), 0, stream, out, out_size,
                               -(4096.f + 32.f * i));
            return;
        }
    }

    const void* inputs = d_in[0];
    const void* triples = d_in[1];
    const void* lengths = d_in[2];
    const void* id2 = d_in[3];
    const float* wordE = (const float*)d_in[4];
    const float* entE = (const float*)d_in[5];
    const float* relE = (const float*)d_in[6];
    const float* Went = (const float*)d_in[7];
    const float* wih = (const float*)d_in[8];
    const float* whh = (const float*)d_in[9];
    const float* bih = (const float*)d_in[10];
    const float* bhh = (const float*)d_in[11];
    const float* Watt = (const float*)d_in[12];
    const float* batt = (const float*)d_in[13];
    const float* Wout = (const float*)d_in[14];
    const float* bout = (const float*)d_in[15];
    char* ws = (char*)d_ws;

    // workspace layout — total 24,901,888 B (< proven 27,028,224)
    // phase k_graph: entE8[0,20e6) graphE[20e6,23.28e6) tok wb trelp flags
    // phase k_gemm : xwB[0,16.78e6) overlays dead entE8; graphE/tokIds/wihT live
    // phase k_lstm : xwB + whhI8; hallB[20e6,24.19e6) overlays dead graphE/wihT-prefix
    constexpr size_t OFF_E8 = 0;             // uchar 200000*100 = 20,000,000
    constexpr size_t OFF_XW = 0;             // ushort 8192*1024*2 = 16,777,216 (overlay)
    constexpr size_t OFF_GE = 20000000;      // ushort 8192*200*2 = 3,276,800
    constexpr size_t OFF_HALL = 20000000;    // ushort 8192*256*2 = 4,194,304 (overlay)
    constexpr size_t OFF_WIHT = 23276800;    // ushort 512*1024*2 = 1,048,576
    constexpr size_t OFF_TOK = 24325376;     // int 8192*4 = 32,768
    constexpr size_t OFF_WHH8 = 24358144;    // uchar 262,144
    constexpr size_t OFF_WB = 24620288;      // ushort 112*256*2 = 57,344
    constexpr size_t OFF_TRELP = 24677632;   // float 500*112*4 = 224,000
    constexpr size_t OFF_FLAGS = 24901632;   // u32 dflag -> end 24,901,888
    constexpr size_t WS_NEEDED = 24901888;

    if (ws_size < WS_NEEDED) {
        hipLaunchKernelGGL(k_sentinel, dim3(ob), dim3(256), 0, stream, out, out_size,
                           -(float)(ws_size >> 20));
        return;
    }

    uchar_t* entE8 = (uchar_t*)(ws + OFF_E8);
    ushort_t* xwB = (ushort_t*)(ws + OFF_XW);
    ushort_t* graphE = (ushort_t*)(ws + OFF_GE);
    ushort_t* hallB = (ushort_t*)(ws + OFF_HALL);
    ushort_t* wihT = (ushort_t*)(ws + OFF_WIHT);
    int* tokIds = (int*)(ws + OFF_TOK);
    uchar_t* whhI8 = (uchar_t*)(ws + OFF_WHH8);
    ushort_t* Wb = (ushort_t*)(ws + OFF_WB);
    unsigned* dflag = (unsigned*)(ws + OFF_FLAGS);
    float* trelP = (float*)(ws + OFF_TRELP);

    hipLaunchKernelGGL(k_det, dim3(1), dim3(256), 0, stream, (const int*)triples, dflag);
    hipLaunchKernelGGL(k_prep, dim3(2048), dim3(256), 0, stream,
                       Went, wih, relE, entE, Wb, wihT, trelP, entE8);
    hipLaunchKernelGGL(k_graph, dim3(8192), dim3(256), 0, stream,
                       inputs, triples, id2, entE8, Wb, trelP, graphE, tokIds, dflag);
    hipLaunchKernelGGL(k_gemm_xw, dim3(128, 16), dim3(256), 0, stream,
                       graphE, tokIds, wordE, wihT, bih, bhh, xwB);
    hipLaunchKernelGGL(k_prep2, dim3(1024), dim3(256), 0, stream, whh, whhI8);
    hipLaunchKernelGGL(k_lstm, dim3(64), dim3(512), 0, stream, xwB, whhI8, lengths, hallB, dflag);
    hipLaunchKernelGGL(k_att, dim3(64), dim3(256), 0, stream, hallB, Watt, batt, Wout, bout, out);
}